// Round 1
// baseline (1723.213 us; speedup 1.0000x reference)
//
#include <hip/hip_runtime.h>
#include <math.h>

#define NNODES 10000
#define NEDGES 160000
#define DIM    256
#define BATCH  4
#define NG     8           // BATCH * S streams
#define MROWS  40064       // buffer row stride (40000 real rows)
#define RBLK   625         // 64-row blocks (gruB)
#define RGRP   79          // ceil(625/8)
#define RBLK128 313        // 128-row blocks (z64/w264/gruA): 313*128 = 40064
#define RGRP128 40         // ceil(313/8)

typedef __attribute__((ext_vector_type(8))) __bf16 bf16x8;
typedef __attribute__((ext_vector_type(4))) float  floatx4;
typedef __attribute__((ext_vector_type(8))) unsigned short ushort8v;

__device__ __forceinline__ float leakyf(float x){ return x > 0.f ? x : 0.01f*x; }
__device__ __forceinline__ float fsig(float x){ return 1.f/(1.f + __expf(-x)); }
__device__ __forceinline__ float ftanh(float x){ return 1.f - 2.f/(1.f + __expf(2.f*x)); }
__device__ __forceinline__ unsigned short f2bf_u(float x){
  unsigned int u = __float_as_uint(x);
  u += 0x7fffu + ((u >> 16) & 1u);
  return (unsigned short)(u >> 16);
}
__device__ __forceinline__ float bfdec(unsigned short u){
  return __uint_as_float(((unsigned int)u) << 16);
}
#define GATE_SCL 65535.f
#define GATE_INV 1.5259021896696422e-5f

__device__ __forceinline__ void glds16(unsigned short* lds, const unsigned short* g){
  __builtin_amdgcn_global_load_lds(
      (const __attribute__((address_space(1))) void*)g,
      (__attribute__((address_space(3))) void*)lds, 16, 0, 0);
}

// h0: nodes -> ihcat0 h-half (hi) + h_lo
__global__ void ihinit_kernel(const float* __restrict__ nodes,
                              unsigned short* __restrict__ ihcat,
                              unsigned short* __restrict__ h_lo){
  int idx = blockIdx.x*256 + threadIdx.x;   // 40000*256
  int row = idx >> 8, d = idx & 255;
  float v = nodes[idx];
  unsigned short h = f2bf_u(v);
  ihcat[(size_t)row*512 + 256 + d] = h;
  h_lo[idx] = f2bf_u(v - bfdec(h));
}

// ---- weight prep ----
__global__ void w1cat_kernel(const float* __restrict__ ew1, unsigned short* __restrict__ o){
  int idx = blockIdx.x*256 + threadIdx.x;      // 512*256
  int n = idx >> 8, k = idx & 255;
  o[idx] = f2bf_u(ew1[(n>>8)*65536 + (n&255)*256 + k]);
}
__global__ void w2k_kernel(const float* __restrict__ ew2, unsigned short* __restrict__ o){
  int idx = blockIdx.x*256 + threadIdx.x;      // 256*1024
  int n = idx >> 10, kp = idx & 1023;
  int j = kp & 511, term = kp >> 9;
  int si = j >> 8, k = j & 255;
  float v = ew2[si*65536 + n*256 + k];
  unsigned short h = f2bf_u(v);
  o[idx] = term ? f2bf_u(v - bfdec(h)) : h;
}
// wk2[c][kp], kp in [0,512): K' = [hi | lo]
__global__ void wk2_kernel(const float* __restrict__ w, unsigned short* __restrict__ o){
  int idx = blockIdx.x*256 + threadIdx.x;      // 768*512
  int c = idx >> 9, kp = idx & 511;
  int k = kp & 255, term = kp >> 8;
  float v = w[c*256 + k];
  unsigned short h = f2bf_u(v);
  o[idx] = term ? f2bf_u(v - bfdec(h)) : h;
}
// wcomb[c][kp], c in [0,512) (r,z rows), kp: [Wih_hi|Whh_hi|Wih_lo|Whh_lo]
__global__ void wcomb_kernel(const float* __restrict__ wih, const float* __restrict__ whh,
                             unsigned short* __restrict__ o){
  int idx = blockIdx.x*256 + threadIdx.x;      // 512*1024
  int c = idx >> 10, kp = idx & 1023;
  int seg = kp >> 8, k = kp & 255;
  const float* w = (seg & 1) ? whh : wih;
  float v = w[c*256 + k];
  unsigned short h = f2bf_u(v);
  o[idx] = (seg >> 1) ? f2bf_u(v - bfdec(h)) : h;
}

// ---------------- edge sort (counting sort by dst, per stream g) ----------------
__global__ void hist_kernel(const int* __restrict__ edges, int* __restrict__ cnt){
  int idx = blockIdx.x*256 + threadIdx.x;
  if (idx < NG*NEDGES){
    int g = idx / NEDGES, e = idx - g*NEDGES;
    int d = edges[((size_t)g*NEDGES + e)*2];
    atomicAdd(&cnt[g*NNODES + d], 1);
  }
}

__global__ __launch_bounds__(256) void scan_kernel(const int* __restrict__ cnt, int* __restrict__ off){
  __shared__ int sc[256];
  int g = blockIdx.x, t = threadIdx.x;
  int base = 0;
  for (int c=0;c<40;c++){
    int i = c*256 + t;
    int v = (i < NNODES) ? cnt[g*NNODES + i] : 0;
    __syncthreads();
    sc[t] = v;
    __syncthreads();
    for (int o=1;o<256;o<<=1){
      int u = (t>=o) ? sc[t-o] : 0;
      __syncthreads();
      sc[t] += u;
      __syncthreads();
    }
    if (i < NNODES) off[g*(NNODES+1) + i] = base + sc[t] - v;
    base += sc[255];
  }
  if (t == 0) off[g*(NNODES+1) + NNODES] = base;
}

__global__ void scatter_kernel(const int* __restrict__ edges, const int* __restrict__ off,
                               int* __restrict__ cur, int* __restrict__ ssrc){
  int idx = blockIdx.x*256 + threadIdx.x;
  if (idx < NG*NEDGES){
    int g = idx / NEDGES, e = idx - g*NEDGES;
    const int* ep = &edges[((size_t)g*NEDGES + e)*2];
    int d = ep[0], s = ep[1];
    int pos = off[g*(NNODES+1) + d] + atomicAdd(&cur[g*NNODES + d], 1);
    ssrc[g*NEDGES + pos] = s;
  }
}

// ================= 64x128 single-buffer LDS-staged MFMA core (gruB) =================
template<int KP, int RS, int KM>
__device__ __forceinline__ void mm64_core(
    const unsigned short* __restrict__ Ab, const unsigned short* __restrict__ Wb,
    unsigned short* lds, floatx4 (&acc)[4][2])
{
  const int t = threadIdx.x;
  const int w = t >> 6, lane = t & 63;
  const int q = lane >> 4, col = lane & 15;
  const int wc = w*32;
  unsigned short* Al = lds;           // 64*64
  unsigned short* Bl = lds + 64*64;   // 128*64

  const int sr = t >> 3;
  const int sj = t & 7;
  const int sk = ((sj ^ (sr & 7)) * 8);

  for (int kb = 0; kb < KP; kb += 64){
    #pragma unroll
    for (int i=0;i<2;i++){
      int r = i*32 + sr;
      glds16(&Al[i*2048 + w*512], &Ab[(size_t)r*RS + ((kb + sk) & KM)]);
    }
    #pragma unroll
    for (int i=0;i<4;i++){
      int r = i*32 + sr;
      glds16(&Bl[i*2048 + w*512], &Wb[(size_t)r*KP + kb + sk]);
    }
    __syncthreads();
    #pragma unroll
    for (int ks2=0; ks2<2; ks2++){
      bf16x8 a[4], bf[2];
      #pragma unroll
      for (int mi=0;mi<4;mi++){
        int r = mi*16 + col;
        int j = (ks2*4 + q) ^ (r & 7);
        a[mi] = *(const bf16x8*)&Al[r*64 + j*8];
      }
      #pragma unroll
      for (int ni=0;ni<2;ni++){
        int r = wc + ni*16 + col;
        int j = (ks2*4 + q) ^ (r & 7);
        bf[ni] = *(const bf16x8*)&Bl[r*64 + j*8];
      }
      #pragma unroll
      for (int mi=0;mi<4;mi++)
        #pragma unroll
        for (int ni=0;ni<2;ni++)
          acc[mi][ni] = __builtin_amdgcn_mfma_f32_16x16x32_bf16(a[mi], bf[ni], acc[mi][ni], 0,0,0);
    }
    __syncthreads();
  }
}

// ================= 128x128 single-buffer LDS-staged MFMA core =================
// Same swizzled staging as mm64_core; 4 waves in 2x2 quadrant layout, acc[4][4].
// Per-output-element K order identical to mm64_core -> bit-identical results.
template<int KP, int RS, int KM>
__device__ __forceinline__ void mm128_core(
    const unsigned short* __restrict__ Ab, const unsigned short* __restrict__ Wb,
    unsigned short* lds, floatx4 (&acc)[4][4])
{
  const int t = threadIdx.x;
  const int w = t >> 6, lane = t & 63;
  const int q = lane >> 4, col = lane & 15;
  const int wr = (w >> 1) * 64;
  const int wc = (w & 1) * 64;
  unsigned short* Al = lds;            // 128*64
  unsigned short* Bl = lds + 128*64;   // 128*64

  const int sr = t >> 3;
  const int sj = t & 7;
  const int sk = ((sj ^ (sr & 7)) * 8);

  for (int kb = 0; kb < KP; kb += 64){
    #pragma unroll
    for (int i=0;i<4;i++){
      int r = i*32 + sr;
      glds16(&Al[i*2048 + w*512], &Ab[(size_t)r*RS + ((kb + sk) & KM)]);
      glds16(&Bl[i*2048 + w*512], &Wb[(size_t)r*KP + kb + sk]);
    }
    __syncthreads();
    #pragma unroll
    for (int ks2=0; ks2<2; ks2++){
      bf16x8 a[4], bf[4];
      #pragma unroll
      for (int mi=0;mi<4;mi++){
        int r = wr + mi*16 + col;
        int j = (ks2*4 + q) ^ (r & 7);
        a[mi] = *(const bf16x8*)&Al[r*64 + j*8];
      }
      #pragma unroll
      for (int ni=0;ni<4;ni++){
        int r = wc + ni*16 + col;
        int j = (ks2*4 + q) ^ (r & 7);
        bf[ni] = *(const bf16x8*)&Bl[r*64 + j*8];
      }
      #pragma unroll
      for (int mi=0;mi<4;mi++)
        #pragma unroll
        for (int ni=0;ni<4;ni++)
          acc[mi][ni] = __builtin_amdgcn_mfma_f32_16x16x32_bf16(a[mi], bf[ni], acc[mi][ni], 0,0,0);
    }
    __syncthreads();
  }
}

// XCD-aligned 1-D grid decode: row-block rb lands on XCD rb%8.
#define XDECODE(NCOL) \
  const int bid_ = blockIdx.x; \
  const int rb_ = ((bid_ >> 3) / NCOL) * 8 + (bid_ & 7); \
  const int colb_ = (bid_ >> 3) % NCOL; \
  if (rb_ >= RBLK) return;

#define XDECODE128(NCOL) \
  const int bid_ = blockIdx.x; \
  const int rb_ = ((bid_ >> 3) / NCOL) * 8 + (bid_ & 7); \
  const int colb_ = (bid_ >> 3) % NCOL; \
  if (rb_ >= RBLK128) return;

#define MMPRO \
  const int t = threadIdx.x, w = t >> 6, lane = t & 63; \
  const int q = lane >> 4, col = lane & 15; \
  const int wc = w*32; \
  floatx4 acc[4][2]; \
  _Pragma("unroll") for (int mi=0;mi<4;mi++) _Pragma("unroll") for (int ni=0;ni<2;ni++) \
    acc[mi][ni] = (floatx4){0.f,0.f,0.f,0.f};

#define MMPRO128 \
  const int t = threadIdx.x, w = t >> 6, lane = t & 63; \
  const int q = lane >> 4, col = lane & 15; \
  const int wrq = (w >> 1) * 64, wcq = (w & 1) * 64; \
  floatx4 acc[4][4]; \
  _Pragma("unroll") for (int mi=0;mi<4;mi++) _Pragma("unroll") for (int ni=0;ni<4;ni++) \
    acc[mi][ni] = (floatx4){0.f,0.f,0.f,0.f};

// ---- Z = leaky(h @ W1cat^T + b1): NCOL=4; h read from ihcat h-half ----
__global__ __launch_bounds__(256) void z64_kernel(
    const unsigned short* __restrict__ ihcat, const unsigned short* __restrict__ w1cat,
    const float* __restrict__ eb1, unsigned short* __restrict__ Z)
{
  __shared__ unsigned short lds[16384];
  XDECODE128(4)
  const int row0 = rb_*128, col0 = colb_*128;
  MMPRO128
  mm128_core<256,512,255>(ihcat + (size_t)row0*512 + 256, w1cat + (size_t)col0*256, lds, acc);

  #pragma unroll
  for (int ni=0;ni<4;ni++){
    int n = col0 + wcq + ni*16 + col;
    int si = n >> 8, cz = n & 255;
    float bb = eb1[si*256 + cz];
    unsigned short* zp = Z + (size_t)si*MROWS*256 + cz;
    #pragma unroll
    for (int mi=0;mi<4;mi++)
      #pragma unroll
      for (int rr=0;rr<4;rr++){
        int row = row0 + wrq + mi*16 + q*4 + rr;
        zp[(size_t)row*256] = f2bf_u(leakyf(acc[mi][ni][rr] + bb));
      }
  }
}

// ---- CSR aggregate, XCD-pinned to stream: g = bid & 7 ----
// Paired-row gather: lanes 0-31 process node d, lanes 32-63 node d+1;
// each 16B/lane load fetches TWO Z rows per instruction. Per-dim FP order
// identical to the serial ushort4 version (4-group + tail, in edge order).
__global__ __launch_bounds__(256) void aggregate_kernel(
    const unsigned short* __restrict__ Z, const int* __restrict__ ssrc,
    const int* __restrict__ off, unsigned short* __restrict__ Sb)
{
  const int bid = blockIdx.x;          // 5000
  const int g = bid & 7;
  const int dgrp = bid >> 3;           // 0..624
  const int b = g >> 1, si = g & 1;
  const int w = threadIdx.x >> 6, lane = threadIdx.x & 63;
  const int half = lane >> 5, c = lane & 31;
  const unsigned short* zb = Z + ((size_t)si*MROWS + b*10000)*256 + c*8;
  const int* sp = ssrc + (size_t)g*NEDGES;
  const int* offg = off + g*(NNODES+1);

  #pragma unroll
  for (int p=0;p<2;p++){
    const int d = dgrp*16 + w*4 + p*2 + half;
    int j = offg[d];
    const int j1 = offg[d+1];
    float a0=0.f,a1=0.f,a2=0.f,a3=0.f,a4=0.f,a5=0.f,a6=0.f,a7=0.f;
    for (; j+4 <= j1; j+=4){
      int s0=sp[j], s1=sp[j+1], s2=sp[j+2], s3=sp[j+3];
      ushort8v u0 = *(const ushort8v*)&zb[(size_t)s0*256];
      ushort8v u1 = *(const ushort8v*)&zb[(size_t)s1*256];
      ushort8v u2 = *(const ushort8v*)&zb[(size_t)s2*256];
      ushort8v u3 = *(const ushort8v*)&zb[(size_t)s3*256];
      a0 += bfdec(u0[0])+bfdec(u1[0])+bfdec(u2[0])+bfdec(u3[0]);
      a1 += bfdec(u0[1])+bfdec(u1[1])+bfdec(u2[1])+bfdec(u3[1]);
      a2 += bfdec(u0[2])+bfdec(u1[2])+bfdec(u2[2])+bfdec(u3[2]);
      a3 += bfdec(u0[3])+bfdec(u1[3])+bfdec(u2[3])+bfdec(u3[3]);
      a4 += bfdec(u0[4])+bfdec(u1[4])+bfdec(u2[4])+bfdec(u3[4]);
      a5 += bfdec(u0[5])+bfdec(u1[5])+bfdec(u2[5])+bfdec(u3[5]);
      a6 += bfdec(u0[6])+bfdec(u1[6])+bfdec(u2[6])+bfdec(u3[6]);
      a7 += bfdec(u0[7])+bfdec(u1[7])+bfdec(u2[7])+bfdec(u3[7]);
    }
    for (; j < j1; j++){
      ushort8v u = *(const ushort8v*)&zb[(size_t)sp[j]*256];
      a0+=bfdec(u[0]); a1+=bfdec(u[1]); a2+=bfdec(u[2]); a3+=bfdec(u[3]);
      a4+=bfdec(u[4]); a5+=bfdec(u[5]); a6+=bfdec(u[6]); a7+=bfdec(u[7]);
    }
    size_t so = (size_t)(b*10000 + d)*512 + si*256 + c*8;
    ushort8v hv;
    hv[0]=f2bf_u(a0); hv[1]=f2bf_u(a1); hv[2]=f2bf_u(a2); hv[3]=f2bf_u(a3);
    hv[4]=f2bf_u(a4); hv[5]=f2bf_u(a5); hv[6]=f2bf_u(a6); hv[7]=f2bf_u(a7);
    *(ushort8v*)&Sb[so] = hv;
  }
}

// ---- ihcat.ib = S @ W2k^T (2-term K'=1024) + deg.b2: NCOL=2 ----
__global__ __launch_bounds__(256) void w264_kernel(
    const unsigned short* __restrict__ Sb, const unsigned short* __restrict__ w2k,
    const float* __restrict__ eb2, const int* __restrict__ off,
    unsigned short* __restrict__ ihcat)
{
  __shared__ unsigned short lds[16384];
  XDECODE128(2)
  const int row0 = rb_*128, col0 = colb_*128;
  MMPRO128
  mm128_core<1024,512,511>(Sb + (size_t)row0*512, w2k + (size_t)col0*1024, lds, acc);

  float b20[4], b21[4];
  #pragma unroll
  for (int ni=0;ni<4;ni++){
    int n = col0 + wcq + ni*16 + col;
    b20[ni] = eb2[n];
    b21[ni] = eb2[256 + n];
  }
  #pragma unroll
  for (int mi=0;mi<4;mi++)
    #pragma unroll
    for (int rr=0;rr<4;rr++){
      int row = row0 + wrq + mi*16 + q*4 + rr;
      int rw = (row < 40000) ? row : 39999;   // guard padding rows (off lookup only)
      int b = rw / 10000, d = rw - b*10000;
      int o0 = (b*2)*(NNODES+1) + d;
      int o1 = (b*2+1)*(NNODES+1) + d;
      float dg0 = (float)(off[o0+1] - off[o0]);
      float dg1 = (float)(off[o1+1] - off[o1]);
      #pragma unroll
      for (int ni=0;ni<4;ni++){
        int n = col0 + wcq + ni*16 + col;
        ihcat[(size_t)row*512 + n] = f2bf_u(acc[mi][ni][rr] + dg0*b20[ni] + dg1*b21[ni]);
      }
    }
}

// ---- gruA: combined r,z GEMM -> u16 gates. NCOL=4 ----
__global__ __launch_bounds__(256) void gruA_kernel(
    const unsigned short* __restrict__ ihcat, const unsigned short* __restrict__ wcomb,
    const float* __restrict__ b_ih, const float* __restrict__ b_hh,
    unsigned short* __restrict__ rz_r, unsigned short* __restrict__ rz_z)
{
  __shared__ unsigned short lds[16384];
  XDECODE128(4)
  const int row0 = rb_*128, col0 = colb_*128;
  MMPRO128
  mm128_core<1024,512,511>(ihcat + (size_t)row0*512, wcomb + (size_t)col0*1024, lds, acc);

  float bb[4];
  #pragma unroll
  for (int ni=0;ni<4;ni++){
    int n = col0 + wcq + ni*16 + col;
    bb[ni] = b_ih[n] + b_hh[n];
  }
  unsigned short* dst = (col0 < 256) ? rz_r : rz_z;
  const int cbase = (col0 & 255) + wcq;
  #pragma unroll
  for (int mi=0;mi<4;mi++)
    #pragma unroll
    for (int rr=0;rr<4;rr++){
      size_t row = (size_t)(row0 + wrq + mi*16 + q*4 + rr);
      #pragma unroll
      for (int ni=0;ni<4;ni++){
        float v = fsig(acc[mi][ni][rr] + bb[ni]);
        dst[row*256 + cbase + ni*16 + col] = (unsigned short)(v*GATE_SCL + 0.5f);
      }
    }
}

// ---- gruB: n gate + GRU update. NCOL=2. Writes ihcat_nxt h-half + h_lo ----
__global__ __launch_bounds__(256) void gruB_kernel(
    const unsigned short* __restrict__ ihcat, unsigned short* __restrict__ h_lo,
    const unsigned short* __restrict__ wihk, const unsigned short* __restrict__ whhk,
    const float* __restrict__ b_ih, const float* __restrict__ b_hh,
    const unsigned short* __restrict__ rz_r, const unsigned short* __restrict__ rz_z,
    unsigned short* __restrict__ ihcat_nxt)
{
  __shared__ unsigned short lds[12288];
  XDECODE(2)
  const int row0 = rb_*64, dcol0 = colb_*128;   // n-gate W cols = 512 + dcol0
  const int t = threadIdx.x, w = t >> 6, lane = t & 63;
  const int q = lane >> 4, col = lane & 15;
  const int wc = w*32;

  floatx4 ai[4][2], ah[4][2];
  #pragma unroll
  for (int mi=0;mi<4;mi++)
    #pragma unroll
    for (int ni=0;ni<2;ni++){ ai[mi][ni] = (floatx4){0.f,0.f,0.f,0.f}; ah[mi][ni] = (floatx4){0.f,0.f,0.f,0.f}; }

  mm64_core<512,512,255>(ihcat + (size_t)row0*512,       wihk + (size_t)(512 + dcol0)*512, lds, ai);
  mm64_core<512,512,255>(ihcat + (size_t)row0*512 + 256, whhk + (size_t)(512 + dcol0)*512, lds, ah);

  float bi[2], bh[2];
  #pragma unroll
  for (int ni=0;ni<2;ni++){
    int n = 512 + dcol0 + wc + ni*16 + col;
    bi[ni] = b_ih[n]; bh[ni] = b_hh[n];
  }
  #pragma unroll
  for (int mi=0;mi<4;mi++)
    #pragma unroll
    for (int rr=0;rr<4;rr++){
      size_t row = (size_t)(row0 + mi*16 + q*4 + rr);
      #pragma unroll
      for (int ni=0;ni<2;ni++){
        int dn = dcol0 + wc + ni*16 + col;
        float rg = (float)rz_r[row*256 + dn] * GATE_INV;
        float zg = (float)rz_z[row*256 + dn] * GATE_INV;
        float ng = ftanh(ai[mi][ni][rr] + bi[ni] + rg*(ah[mi][ni][rr] + bh[ni]));
        float hv = bfdec(ihcat[row*512 + 256 + dn]) + bfdec(h_lo[row*256 + dn]);
        float hnew = (1.f - zg)*ng + zg*hv;
        unsigned short hh = f2bf_u(hnew);
        ihcat_nxt[row*512 + 256 + dn] = hh;
        h_lo[row*256 + dn] = f2bf_u(hnew - bfdec(hh));
      }
    }
}

__global__ void reduce_kernel(const unsigned short* __restrict__ ihcat,
                              const unsigned short* __restrict__ h_lo,
                              float* __restrict__ sbuf){
  int b  = blockIdx.x / 50;
  int s0 = (blockIdx.x % 50) * 200;
  int d  = threadIdx.x;
  size_t row = (size_t)b*NNODES + s0;
  float acc = 0.f;
  for (int i=0;i<200;i++){
    acc += bfdec(ihcat[(row+i)*512 + 256 + d]) + bfdec(h_lo[(row+i)*256 + d]);
  }
  atomicAdd(&sbuf[b*DIM + d], acc);
}

__global__ __launch_bounds__(320) void head_kernel(
    const float* __restrict__ sbuf, const float* __restrict__ pt,
    const float* __restrict__ fc1w, const float* __restrict__ fc1b,
    const float* __restrict__ fc2w, const float* __restrict__ fc2b,
    const float* __restrict__ fc3w, const float* __restrict__ fc3b,
    float* __restrict__ out)
{
  __shared__ float L[4][257];
  __shared__ float T1[4][80];
  __shared__ float T2[4][80];
  __shared__ float fmx[4];
  int t = threadIdx.x;
  if (t < 256){
    for (int b=0;b<4;b++){
      float v = sbuf[b*DIM + t];
      float ll = logf(v);
      if (ll != ll) ll = 0.f;
      ll = fmaxf(ll, 0.f);
      L[b][t] = ll;
    }
  }
  __syncthreads();
  int w = t >> 6, lane = t & 63;
  if (w < 4){
    float m = -INFINITY;
    for (int i=lane;i<256;i+=64){ float v = L[w][i]; if (v != INFINITY) m = fmaxf(m, v); }
    #pragma unroll
    for (int o=32;o>=1;o>>=1) m = fmaxf(m, __shfl_xor(m, o, 64));
    if (lane==0) fmx[w] = m;
  }
  __syncthreads();
  if (t < 256){
    for (int b=0;b<4;b++) if (L[b][t] == INFINITY) L[b][t] = fmx[b];
  }
  if (t < 4) L[t][256] = pt[t];
  __syncthreads();
  if (t < 320){
    int b = t/80, i = t%80;
    float a = fc1b[i];
    for (int k=0;k<257;k++) a += L[b][k]*fc1w[i*257+k];
    T1[b][i] = leakyf(a);
  }
  __syncthreads();
  if (t < 320){
    int b = t/80, i = t%80;
    float a = fc2b[i];
    for (int k=0;k<80;k++) a += T1[b][k]*fc2w[i*80+k];
    T2[b][i] = leakyf(a);
  }
  __syncthreads();
  if (t < 40){
    int b = t/10, i = t%10;
    float a = fc3b[i];
    for (int k=0;k<80;k++) a += T2[b][k]*fc3w[i*80+k];
    out[b*10+i] = a;
  }
}

extern "C" void kernel_launch(void* const* d_in, const int* in_sizes, int n_in,
                              void* d_out, int out_size, void* d_ws, size_t ws_size,
                              hipStream_t stream) {
  const float* nodes = (const float*)d_in[0];
  const int*   edges = (const int*)d_in[1];
  const float* pt    = (const float*)d_in[2];
  const float* w_ih  = (const float*)d_in[3];
  const float* w_hh  = (const float*)d_in[4];
  const float* b_ih  = (const float*)d_in[5];
  const float* b_hh  = (const float*)d_in[6];
  const float* ew1   = (const float*)d_in[7];
  const float* eb1   = (const float*)d_in[8];
  const float* ew2   = (const float*)d_in[9];
  const float* eb2   = (const float*)d_in[10];
  const float* fc1w  = (const float*)d_in[11];
  const float* fc1b  = (const float*)d_in[12];
  const float* fc2w  = (const float*)d_in[13];
  const float* fc2b  = (const float*)d_in[14];
  const float* fc3w  = (const float*)d_in[15];
  const float* fc3b  = (const float*)d_in[16];

  const size_t HN  = (size_t)BATCH*NNODES*DIM;    // 10,240,000 (real rows)
  const size_t HNP = (size_t)MROWS*DIM;
  char* p = (char*)d_ws;
  float* sbuf = (float*)p;                        p += BATCH*DIM*4;
  unsigned short* ihcat0 = (unsigned short*)p;    p += (size_t)MROWS*512*2;  // [ib | h]
  unsigned short* ihcat1 = (unsigned short*)p;    p += (size_t)MROWS*512*2;
  unsigned short* h_lo   = (unsigned short*)p;    p += HNP*2;
  unsigned short* Zb   = (unsigned short*)p;      p += 2*HNP*2;              // z/agg scratch
  unsigned short* Sb   = (unsigned short*)p;      p += (size_t)MROWS*512*2;  // dead after w2 -> rz
  unsigned short* w1cat= (unsigned short*)p;      p += 512*256*2;
  unsigned short* w2k  = (unsigned short*)p;      p += 256*1024*2;
  unsigned short* wihk = (unsigned short*)p;      p += 768*512*2;
  unsigned short* whhk = (unsigned short*)p;      p += 768*512*2;
  unsigned short* wcomb= (unsigned short*)p;      p += 512*1024*2;
  int* off  = (int*)p;                            p += NG*(NNODES+1)*4;
  int* cur  = (int*)p;                            p += NG*NNODES*4;
  int* ssrc = (int*)p;                            p += (size_t)NG*NEDGES*4;

  unsigned short* rz_r = (unsigned short*)Sb;              // MROWS*256 u16
  unsigned short* rz_z = rz_r + (size_t)MROWS*256;         // MROWS*256 u16

  // weights
  w1cat_kernel<<<512,256,0,stream>>>(ew1, w1cat);
  w2k_kernel<<<1024,256,0,stream>>>(ew2, w2k);
  wk2_kernel<<<1536,256,0,stream>>>(w_ih, wihk);
  wk2_kernel<<<1536,256,0,stream>>>(w_hh, whhk);
  wcomb_kernel<<<2048,256,0,stream>>>(w_ih, w_hh, wcomb);

  // h0
  ihinit_kernel<<<(int)(HN/256),256,0,stream>>>(nodes, ihcat0, h_lo);

  // counting sort (CSR) of edges by dst, per stream g
  hipMemsetAsync(cur, 0, NG*NNODES*sizeof(int), stream);
  hist_kernel<<<(NG*NEDGES)/256,256,0,stream>>>(edges, cur);
  scan_kernel<<<NG,256,0,stream>>>(cur, off);
  hipMemsetAsync(cur, 0, NG*NNODES*sizeof(int), stream);
  scatter_kernel<<<(NG*NEDGES)/256,256,0,stream>>>(edges, off, cur, ssrc);

  hipMemsetAsync(sbuf, 0, BATCH*DIM*sizeof(float), stream);

  unsigned short* ih[2] = {ihcat0, ihcat1};

  for (int pass=0; pass<6; pass++){
    unsigned short* curb = ih[pass & 1];
    unsigned short* nxtb = ih[(pass+1) & 1];
    z64_kernel<<<RGRP128*8*4,256,0,stream>>>(curb, w1cat, eb1, Zb);
    aggregate_kernel<<<5000,256,0,stream>>>(Zb, ssrc, off, Sb);
    w264_kernel<<<RGRP128*8*2,256,0,stream>>>(Sb, w2k, eb2, off, curb);
    gruA_kernel<<<RGRP128*8*4,256,0,stream>>>(curb, wcomb, b_ih, b_hh, rz_r, rz_z);
    gruB_kernel<<<RGRP*8*2,256,0,stream>>>(curb, h_lo, wihk, whhk, b_ih, b_hh,
                                           rz_r, rz_z, nxtb);
  }
  reduce_kernel<<<200,256,0,stream>>>(ih[0], h_lo, sbuf);
  head_kernel<<<1,320,0,stream>>>(sbuf, pt, fc1w,fc1b,fc2w,fc2b,fc3w,fc3b,(float*)d_out);
}

// Round 2
// 1701.726 us; speedup vs baseline: 1.0126x; 1.0126x over previous
//
#include <hip/hip_runtime.h>
#include <math.h>

#define NNODES 10000
#define NEDGES 160000
#define DIM    256
#define BATCH  4
#define NG     8           // BATCH * S streams
#define MROWS  40064       // buffer row stride (40000 real rows)
#define RBLK   625         // 64-row blocks (gruB)
#define RGRP   79          // ceil(625/8)
#define RBLK128 313        // 128-row blocks (z64/w264/gruA): 313*128 = 40064
#define RGRP128 40         // ceil(313/8)

typedef __attribute__((ext_vector_type(8))) __bf16 bf16x8;
typedef __attribute__((ext_vector_type(4))) float  floatx4;
typedef __attribute__((ext_vector_type(8))) unsigned short ushort8v;

__device__ __forceinline__ float leakyf(float x){ return x > 0.f ? x : 0.01f*x; }
__device__ __forceinline__ float fsig(float x){ return 1.f/(1.f + __expf(-x)); }
__device__ __forceinline__ float ftanh(float x){ return 1.f - 2.f/(1.f + __expf(2.f*x)); }
__device__ __forceinline__ unsigned short f2bf_u(float x){
  unsigned int u = __float_as_uint(x);
  u += 0x7fffu + ((u >> 16) & 1u);
  return (unsigned short)(u >> 16);
}
__device__ __forceinline__ float bfdec(unsigned short u){
  return __uint_as_float(((unsigned int)u) << 16);
}
#define GATE_SCL 65535.f
#define GATE_INV 1.5259021896696422e-5f

__device__ __forceinline__ void glds16(unsigned short* lds, const unsigned short* g){
  __builtin_amdgcn_global_load_lds(
      (const __attribute__((address_space(1))) void*)g,
      (__attribute__((address_space(3))) void*)lds, 16, 0, 0);
}

// h0: nodes -> ihcat0 h-half (hi) + h_lo
__global__ void ihinit_kernel(const float* __restrict__ nodes,
                              unsigned short* __restrict__ ihcat,
                              unsigned short* __restrict__ h_lo){
  int idx = blockIdx.x*256 + threadIdx.x;   // 40000*256
  int row = idx >> 8, d = idx & 255;
  float v = nodes[idx];
  unsigned short h = f2bf_u(v);
  ihcat[(size_t)row*512 + 256 + d] = h;
  h_lo[idx] = f2bf_u(v - bfdec(h));
}

// ---- weight prep ----
__global__ void w1cat_kernel(const float* __restrict__ ew1, unsigned short* __restrict__ o){
  int idx = blockIdx.x*256 + threadIdx.x;      // 512*256
  int n = idx >> 8, k = idx & 255;
  o[idx] = f2bf_u(ew1[(n>>8)*65536 + (n&255)*256 + k]);
}
__global__ void w2k_kernel(const float* __restrict__ ew2, unsigned short* __restrict__ o){
  int idx = blockIdx.x*256 + threadIdx.x;      // 256*1024
  int n = idx >> 10, kp = idx & 1023;
  int j = kp & 511, term = kp >> 9;
  int si = j >> 8, k = j & 255;
  float v = ew2[si*65536 + n*256 + k];
  unsigned short h = f2bf_u(v);
  o[idx] = term ? f2bf_u(v - bfdec(h)) : h;
}
// wk2[c][kp], kp in [0,512): K' = [hi | lo]
__global__ void wk2_kernel(const float* __restrict__ w, unsigned short* __restrict__ o){
  int idx = blockIdx.x*256 + threadIdx.x;      // 768*512
  int c = idx >> 9, kp = idx & 511;
  int k = kp & 255, term = kp >> 8;
  float v = w[c*256 + k];
  unsigned short h = f2bf_u(v);
  o[idx] = term ? f2bf_u(v - bfdec(h)) : h;
}
// wcomb[c][kp], c in [0,512) (r,z rows), kp: [Wih_hi|Whh_hi|Wih_lo|Whh_lo]
__global__ void wcomb_kernel(const float* __restrict__ wih, const float* __restrict__ whh,
                             unsigned short* __restrict__ o){
  int idx = blockIdx.x*256 + threadIdx.x;      // 512*1024
  int c = idx >> 10, kp = idx & 1023;
  int seg = kp >> 8, k = kp & 255;
  const float* w = (seg & 1) ? whh : wih;
  float v = w[c*256 + k];
  unsigned short h = f2bf_u(v);
  o[idx] = (seg >> 1) ? f2bf_u(v - bfdec(h)) : h;
}

// ---------------- edge sort (counting sort by dst, per stream g) ----------------
__global__ void hist_kernel(const int* __restrict__ edges, int* __restrict__ cnt){
  int idx = blockIdx.x*256 + threadIdx.x;
  if (idx < NG*NEDGES){
    int g = idx / NEDGES, e = idx - g*NEDGES;
    int d = edges[((size_t)g*NEDGES + e)*2];
    atomicAdd(&cnt[g*NNODES + d], 1);
  }
}

__global__ __launch_bounds__(256) void scan_kernel(const int* __restrict__ cnt, int* __restrict__ off){
  __shared__ int sc[256];
  int g = blockIdx.x, t = threadIdx.x;
  int base = 0;
  for (int c=0;c<40;c++){
    int i = c*256 + t;
    int v = (i < NNODES) ? cnt[g*NNODES + i] : 0;
    __syncthreads();
    sc[t] = v;
    __syncthreads();
    for (int o=1;o<256;o<<=1){
      int u = (t>=o) ? sc[t-o] : 0;
      __syncthreads();
      sc[t] += u;
      __syncthreads();
    }
    if (i < NNODES) off[g*(NNODES+1) + i] = base + sc[t] - v;
    base += sc[255];
  }
  if (t == 0) off[g*(NNODES+1) + NNODES] = base;
}

__global__ void scatter_kernel(const int* __restrict__ edges, const int* __restrict__ off,
                               int* __restrict__ cur, int* __restrict__ ssrc){
  int idx = blockIdx.x*256 + threadIdx.x;
  if (idx < NG*NEDGES){
    int g = idx / NEDGES, e = idx - g*NEDGES;
    const int* ep = &edges[((size_t)g*NEDGES + e)*2];
    int d = ep[0], s = ep[1];
    int pos = off[g*(NNODES+1) + d] + atomicAdd(&cur[g*NNODES + d], 1);
    ssrc[g*NEDGES + pos] = s;
  }
}

// ========== 64x128 double-buffered 2-phase LDS-staged MFMA core (gruB) ==========
// Buffers at lds + b*12288 (A 64*64 at +0, B 128*64 at +4096). One barrier/step;
// next step's global_load_lds issued BEFORE current step's ds_read+MFMA.
template<int KP, int RS, int KM>
__device__ __forceinline__ void mm64_core(
    const unsigned short* __restrict__ Ab, const unsigned short* __restrict__ Wb,
    unsigned short* lds, floatx4 (&acc)[4][2])
{
  const int t = threadIdx.x;
  const int w = t >> 6, lane = t & 63;
  const int q = lane >> 4, col = lane & 15;
  const int wc = w*32;

  const int sr = t >> 3;
  const int sj = t & 7;
  const int sk = ((sj ^ (sr & 7)) * 8);

  {
    unsigned short* Al = lds;
    unsigned short* Bl = lds + 4096;
    #pragma unroll
    for (int i=0;i<2;i++){
      int r = i*32 + sr;
      glds16(&Al[i*2048 + w*512], &Ab[(size_t)r*RS + (sk & KM)]);
    }
    #pragma unroll
    for (int i=0;i<4;i++){
      int r = i*32 + sr;
      glds16(&Bl[i*2048 + w*512], &Wb[(size_t)r*KP + sk]);
    }
  }
  __syncthreads();
  int cur = 0;
  for (int kb = 0; kb < KP; kb += 64){
    if (kb + 64 < KP){
      unsigned short* Al = lds + (cur^1)*12288;
      unsigned short* Bl = Al + 4096;
      int kn = kb + 64;
      #pragma unroll
      for (int i=0;i<2;i++){
        int r = i*32 + sr;
        glds16(&Al[i*2048 + w*512], &Ab[(size_t)r*RS + ((kn + sk) & KM)]);
      }
      #pragma unroll
      for (int i=0;i<4;i++){
        int r = i*32 + sr;
        glds16(&Bl[i*2048 + w*512], &Wb[(size_t)r*KP + kn + sk]);
      }
    }
    const unsigned short* Al = lds + cur*12288;
    const unsigned short* Bl = Al + 4096;
    #pragma unroll
    for (int ks2=0; ks2<2; ks2++){
      bf16x8 a[4], bf[2];
      #pragma unroll
      for (int mi=0;mi<4;mi++){
        int r = mi*16 + col;
        int j = (ks2*4 + q) ^ (r & 7);
        a[mi] = *(const bf16x8*)&Al[r*64 + j*8];
      }
      #pragma unroll
      for (int ni=0;ni<2;ni++){
        int r = wc + ni*16 + col;
        int j = (ks2*4 + q) ^ (r & 7);
        bf[ni] = *(const bf16x8*)&Bl[r*64 + j*8];
      }
      #pragma unroll
      for (int mi=0;mi<4;mi++)
        #pragma unroll
        for (int ni=0;ni<2;ni++)
          acc[mi][ni] = __builtin_amdgcn_mfma_f32_16x16x32_bf16(a[mi], bf[ni], acc[mi][ni], 0,0,0);
    }
    __syncthreads();
    cur ^= 1;
  }
}

// ========== 128x128 double-buffered 2-phase LDS-staged MFMA core ==========
// Buffers at lds + b*16384 (A 128*64 at +0, B 128*64 at +8192). Same compute
// order as the single-buffer version -> bit-identical results.
template<int KP, int RS, int KM>
__device__ __forceinline__ void mm128_core(
    const unsigned short* __restrict__ Ab, const unsigned short* __restrict__ Wb,
    unsigned short* lds, floatx4 (&acc)[4][4])
{
  const int t = threadIdx.x;
  const int w = t >> 6, lane = t & 63;
  const int q = lane >> 4, col = lane & 15;
  const int wr = (w >> 1) * 64;
  const int wc = (w & 1) * 64;

  const int sr = t >> 3;
  const int sj = t & 7;
  const int sk = ((sj ^ (sr & 7)) * 8);

  {
    unsigned short* Al = lds;
    unsigned short* Bl = lds + 8192;
    #pragma unroll
    for (int i=0;i<4;i++){
      int r = i*32 + sr;
      glds16(&Al[i*2048 + w*512], &Ab[(size_t)r*RS + (sk & KM)]);
      glds16(&Bl[i*2048 + w*512], &Wb[(size_t)r*KP + sk]);
    }
  }
  __syncthreads();
  int cur = 0;
  for (int kb = 0; kb < KP; kb += 64){
    if (kb + 64 < KP){
      unsigned short* Al = lds + (cur^1)*16384;
      unsigned short* Bl = Al + 8192;
      int kn = kb + 64;
      #pragma unroll
      for (int i=0;i<4;i++){
        int r = i*32 + sr;
        glds16(&Al[i*2048 + w*512], &Ab[(size_t)r*RS + ((kn + sk) & KM)]);
        glds16(&Bl[i*2048 + w*512], &Wb[(size_t)r*KP + kn + sk]);
      }
    }
    const unsigned short* Al = lds + cur*16384;
    const unsigned short* Bl = Al + 8192;
    #pragma unroll
    for (int ks2=0; ks2<2; ks2++){
      bf16x8 a[4], bf[4];
      #pragma unroll
      for (int mi=0;mi<4;mi++){
        int r = wr + mi*16 + col;
        int j = (ks2*4 + q) ^ (r & 7);
        a[mi] = *(const bf16x8*)&Al[r*64 + j*8];
      }
      #pragma unroll
      for (int ni=0;ni<4;ni++){
        int r = wc + ni*16 + col;
        int j = (ks2*4 + q) ^ (r & 7);
        bf[ni] = *(const bf16x8*)&Bl[r*64 + j*8];
      }
      #pragma unroll
      for (int mi=0;mi<4;mi++)
        #pragma unroll
        for (int ni=0;ni<4;ni++)
          acc[mi][ni] = __builtin_amdgcn_mfma_f32_16x16x32_bf16(a[mi], bf[ni], acc[mi][ni], 0,0,0);
    }
    __syncthreads();
    cur ^= 1;
  }
}

// XCD-aligned 1-D grid decode: row-block rb lands on XCD rb%8.
#define XDECODE(NCOL) \
  const int bid_ = blockIdx.x; \
  const int rb_ = ((bid_ >> 3) / NCOL) * 8 + (bid_ & 7); \
  const int colb_ = (bid_ >> 3) % NCOL; \
  if (rb_ >= RBLK) return;

#define XDECODE128(NCOL) \
  const int bid_ = blockIdx.x; \
  const int rb_ = ((bid_ >> 3) / NCOL) * 8 + (bid_ & 7); \
  const int colb_ = (bid_ >> 3) % NCOL; \
  if (rb_ >= RBLK128) return;

#define MMPRO \
  const int t = threadIdx.x, w = t >> 6, lane = t & 63; \
  const int q = lane >> 4, col = lane & 15; \
  const int wc = w*32; \
  floatx4 acc[4][2]; \
  _Pragma("unroll") for (int mi=0;mi<4;mi++) _Pragma("unroll") for (int ni=0;ni<2;ni++) \
    acc[mi][ni] = (floatx4){0.f,0.f,0.f,0.f};

#define MMPRO128 \
  const int t = threadIdx.x, w = t >> 6, lane = t & 63; \
  const int q = lane >> 4, col = lane & 15; \
  const int wrq = (w >> 1) * 64, wcq = (w & 1) * 64; \
  floatx4 acc[4][4]; \
  _Pragma("unroll") for (int mi=0;mi<4;mi++) _Pragma("unroll") for (int ni=0;ni<4;ni++) \
    acc[mi][ni] = (floatx4){0.f,0.f,0.f,0.f};

// ---- Z = leaky(h @ W1cat^T + b1): NCOL=4; h read from ihcat h-half ----
__global__ __launch_bounds__(256) void z64_kernel(
    const unsigned short* __restrict__ ihcat, const unsigned short* __restrict__ w1cat,
    const float* __restrict__ eb1, unsigned short* __restrict__ Z)
{
  __shared__ unsigned short lds[32768];
  XDECODE128(4)
  const int row0 = rb_*128, col0 = colb_*128;
  MMPRO128
  mm128_core<256,512,255>(ihcat + (size_t)row0*512 + 256, w1cat + (size_t)col0*256, lds, acc);

  #pragma unroll
  for (int ni=0;ni<4;ni++){
    int n = col0 + wcq + ni*16 + col;
    int si = n >> 8, cz = n & 255;
    float bb = eb1[si*256 + cz];
    unsigned short* zp = Z + (size_t)si*MROWS*256 + cz;
    #pragma unroll
    for (int mi=0;mi<4;mi++)
      #pragma unroll
      for (int rr=0;rr<4;rr++){
        int row = row0 + wrq + mi*16 + q*4 + rr;
        zp[(size_t)row*256] = f2bf_u(leakyf(acc[mi][ni][rr] + bb));
      }
  }
}

// ---- CSR aggregate, XCD-pinned to stream: g = bid & 7 ----
// Paired-row gather: lanes 0-31 process node d, lanes 32-63 node d+1.
// Unroll-8: 8 gathered rows in flight per lane; sums done as two sequential
// 4-groups so FP order is identical to the 4-unrolled loop.
__global__ __launch_bounds__(256) void aggregate_kernel(
    const unsigned short* __restrict__ Z, const int* __restrict__ ssrc,
    const int* __restrict__ off, unsigned short* __restrict__ Sb)
{
  const int bid = blockIdx.x;          // 5000
  const int g = bid & 7;
  const int dgrp = bid >> 3;           // 0..624
  const int b = g >> 1, si = g & 1;
  const int w = threadIdx.x >> 6, lane = threadIdx.x & 63;
  const int half = lane >> 5, c = lane & 31;
  const unsigned short* zb = Z + ((size_t)si*MROWS + b*10000)*256 + c*8;
  const int* sp = ssrc + (size_t)g*NEDGES;
  const int* offg = off + g*(NNODES+1);

  #pragma unroll
  for (int p=0;p<2;p++){
    const int d = dgrp*16 + w*4 + p*2 + half;
    int j = offg[d];
    const int j1 = offg[d+1];
    float a0=0.f,a1=0.f,a2=0.f,a3=0.f,a4=0.f,a5=0.f,a6=0.f,a7=0.f;
    for (; j+8 <= j1; j+=8){
      int s[8];
      #pragma unroll
      for (int e=0;e<8;e++) s[e] = sp[j+e];
      ushort8v u[8];
      #pragma unroll
      for (int e=0;e<8;e++) u[e] = *(const ushort8v*)&zb[(size_t)s[e]*256];
      a0 += bfdec(u[0][0])+bfdec(u[1][0])+bfdec(u[2][0])+bfdec(u[3][0]);
      a1 += bfdec(u[0][1])+bfdec(u[1][1])+bfdec(u[2][1])+bfdec(u[3][1]);
      a2 += bfdec(u[0][2])+bfdec(u[1][2])+bfdec(u[2][2])+bfdec(u[3][2]);
      a3 += bfdec(u[0][3])+bfdec(u[1][3])+bfdec(u[2][3])+bfdec(u[3][3]);
      a4 += bfdec(u[0][4])+bfdec(u[1][4])+bfdec(u[2][4])+bfdec(u[3][4]);
      a5 += bfdec(u[0][5])+bfdec(u[1][5])+bfdec(u[2][5])+bfdec(u[3][5]);
      a6 += bfdec(u[0][6])+bfdec(u[1][6])+bfdec(u[2][6])+bfdec(u[3][6]);
      a7 += bfdec(u[0][7])+bfdec(u[1][7])+bfdec(u[2][7])+bfdec(u[3][7]);
      a0 += bfdec(u[4][0])+bfdec(u[5][0])+bfdec(u[6][0])+bfdec(u[7][0]);
      a1 += bfdec(u[4][1])+bfdec(u[5][1])+bfdec(u[6][1])+bfdec(u[7][1]);
      a2 += bfdec(u[4][2])+bfdec(u[5][2])+bfdec(u[6][2])+bfdec(u[7][2]);
      a3 += bfdec(u[4][3])+bfdec(u[5][3])+bfdec(u[6][3])+bfdec(u[7][3]);
      a4 += bfdec(u[4][4])+bfdec(u[5][4])+bfdec(u[6][4])+bfdec(u[7][4]);
      a5 += bfdec(u[4][5])+bfdec(u[5][5])+bfdec(u[6][5])+bfdec(u[7][5]);
      a6 += bfdec(u[4][6])+bfdec(u[5][6])+bfdec(u[6][6])+bfdec(u[7][6]);
      a7 += bfdec(u[4][7])+bfdec(u[5][7])+bfdec(u[6][7])+bfdec(u[7][7]);
    }
    for (; j+4 <= j1; j+=4){
      int s0=sp[j], s1=sp[j+1], s2=sp[j+2], s3=sp[j+3];
      ushort8v u0 = *(const ushort8v*)&zb[(size_t)s0*256];
      ushort8v u1 = *(const ushort8v*)&zb[(size_t)s1*256];
      ushort8v u2 = *(const ushort8v*)&zb[(size_t)s2*256];
      ushort8v u3 = *(const ushort8v*)&zb[(size_t)s3*256];
      a0 += bfdec(u0[0])+bfdec(u1[0])+bfdec(u2[0])+bfdec(u3[0]);
      a1 += bfdec(u0[1])+bfdec(u1[1])+bfdec(u2[1])+bfdec(u3[1]);
      a2 += bfdec(u0[2])+bfdec(u1[2])+bfdec(u2[2])+bfdec(u3[2]);
      a3 += bfdec(u0[3])+bfdec(u1[3])+bfdec(u2[3])+bfdec(u3[3]);
      a4 += bfdec(u0[4])+bfdec(u1[4])+bfdec(u2[4])+bfdec(u3[4]);
      a5 += bfdec(u0[5])+bfdec(u1[5])+bfdec(u2[5])+bfdec(u3[5]);
      a6 += bfdec(u0[6])+bfdec(u1[6])+bfdec(u2[6])+bfdec(u3[6]);
      a7 += bfdec(u0[7])+bfdec(u1[7])+bfdec(u2[7])+bfdec(u3[7]);
    }
    for (; j < j1; j++){
      ushort8v u = *(const ushort8v*)&zb[(size_t)sp[j]*256];
      a0+=bfdec(u[0]); a1+=bfdec(u[1]); a2+=bfdec(u[2]); a3+=bfdec(u[3]);
      a4+=bfdec(u[4]); a5+=bfdec(u[5]); a6+=bfdec(u[6]); a7+=bfdec(u[7]);
    }
    size_t so = (size_t)(b*10000 + d)*512 + si*256 + c*8;
    ushort8v hv;
    hv[0]=f2bf_u(a0); hv[1]=f2bf_u(a1); hv[2]=f2bf_u(a2); hv[3]=f2bf_u(a3);
    hv[4]=f2bf_u(a4); hv[5]=f2bf_u(a5); hv[6]=f2bf_u(a6); hv[7]=f2bf_u(a7);
    *(ushort8v*)&Sb[so] = hv;
  }
}

// ---- ihcat.ib = S @ W2k^T (2-term K'=1024) + deg.b2: NCOL=2 ----
__global__ __launch_bounds__(256) void w264_kernel(
    const unsigned short* __restrict__ Sb, const unsigned short* __restrict__ w2k,
    const float* __restrict__ eb2, const int* __restrict__ off,
    unsigned short* __restrict__ ihcat)
{
  __shared__ unsigned short lds[32768];
  XDECODE128(2)
  const int row0 = rb_*128, col0 = colb_*128;
  MMPRO128
  mm128_core<1024,512,511>(Sb + (size_t)row0*512, w2k + (size_t)col0*1024, lds, acc);

  float b20[4], b21[4];
  #pragma unroll
  for (int ni=0;ni<4;ni++){
    int n = col0 + wcq + ni*16 + col;
    b20[ni] = eb2[n];
    b21[ni] = eb2[256 + n];
  }
  #pragma unroll
  for (int mi=0;mi<4;mi++)
    #pragma unroll
    for (int rr=0;rr<4;rr++){
      int row = row0 + wrq + mi*16 + q*4 + rr;
      int rw = (row < 40000) ? row : 39999;   // guard padding rows (off lookup only)
      int b = rw / 10000, d = rw - b*10000;
      int o0 = (b*2)*(NNODES+1) + d;
      int o1 = (b*2+1)*(NNODES+1) + d;
      float dg0 = (float)(off[o0+1] - off[o0]);
      float dg1 = (float)(off[o1+1] - off[o1]);
      #pragma unroll
      for (int ni=0;ni<4;ni++){
        int n = col0 + wcq + ni*16 + col;
        ihcat[(size_t)row*512 + n] = f2bf_u(acc[mi][ni][rr] + dg0*b20[ni] + dg1*b21[ni]);
      }
    }
}

// ---- gruA: combined r,z GEMM -> u16 gates. NCOL=4 ----
__global__ __launch_bounds__(256) void gruA_kernel(
    const unsigned short* __restrict__ ihcat, const unsigned short* __restrict__ wcomb,
    const float* __restrict__ b_ih, const float* __restrict__ b_hh,
    unsigned short* __restrict__ rz_r, unsigned short* __restrict__ rz_z)
{
  __shared__ unsigned short lds[32768];
  XDECODE128(4)
  const int row0 = rb_*128, col0 = colb_*128;
  MMPRO128
  mm128_core<1024,512,511>(ihcat + (size_t)row0*512, wcomb + (size_t)col0*1024, lds, acc);

  float bb[4];
  #pragma unroll
  for (int ni=0;ni<4;ni++){
    int n = col0 + wcq + ni*16 + col;
    bb[ni] = b_ih[n] + b_hh[n];
  }
  unsigned short* dst = (col0 < 256) ? rz_r : rz_z;
  const int cbase = (col0 & 255) + wcq;
  #pragma unroll
  for (int mi=0;mi<4;mi++)
    #pragma unroll
    for (int rr=0;rr<4;rr++){
      size_t row = (size_t)(row0 + wrq + mi*16 + q*4 + rr);
      #pragma unroll
      for (int ni=0;ni<4;ni++){
        float v = fsig(acc[mi][ni][rr] + bb[ni]);
        dst[row*256 + cbase + ni*16 + col] = (unsigned short)(v*GATE_SCL + 0.5f);
      }
    }
}

// ---- gruB: n gate + GRU update. NCOL=2. Writes ihcat_nxt h-half + h_lo ----
__global__ __launch_bounds__(256) void gruB_kernel(
    const unsigned short* __restrict__ ihcat, unsigned short* __restrict__ h_lo,
    const unsigned short* __restrict__ wihk, const unsigned short* __restrict__ whhk,
    const float* __restrict__ b_ih, const float* __restrict__ b_hh,
    const unsigned short* __restrict__ rz_r, const unsigned short* __restrict__ rz_z,
    unsigned short* __restrict__ ihcat_nxt)
{
  __shared__ unsigned short lds[24576];
  XDECODE(2)
  const int row0 = rb_*64, dcol0 = colb_*128;   // n-gate W cols = 512 + dcol0
  const int t = threadIdx.x, w = t >> 6, lane = t & 63;
  const int q = lane >> 4, col = lane & 15;
  const int wc = w*32;

  floatx4 ai[4][2], ah[4][2];
  #pragma unroll
  for (int mi=0;mi<4;mi++)
    #pragma unroll
    for (int ni=0;ni<2;ni++){ ai[mi][ni] = (floatx4){0.f,0.f,0.f,0.f}; ah[mi][ni] = (floatx4){0.f,0.f,0.f,0.f}; }

  mm64_core<512,512,255>(ihcat + (size_t)row0*512,       wihk + (size_t)(512 + dcol0)*512, lds, ai);
  mm64_core<512,512,255>(ihcat + (size_t)row0*512 + 256, whhk + (size_t)(512 + dcol0)*512, lds, ah);

  float bi[2], bh[2];
  #pragma unroll
  for (int ni=0;ni<2;ni++){
    int n = 512 + dcol0 + wc + ni*16 + col;
    bi[ni] = b_ih[n]; bh[ni] = b_hh[n];
  }
  #pragma unroll
  for (int mi=0;mi<4;mi++)
    #pragma unroll
    for (int rr=0;rr<4;rr++){
      size_t row = (size_t)(row0 + mi*16 + q*4 + rr);
      #pragma unroll
      for (int ni=0;ni<2;ni++){
        int dn = dcol0 + wc + ni*16 + col;
        float rg = (float)rz_r[row*256 + dn] * GATE_INV;
        float zg = (float)rz_z[row*256 + dn] * GATE_INV;
        float ng = ftanh(ai[mi][ni][rr] + bi[ni] + rg*(ah[mi][ni][rr] + bh[ni]));
        float hv = bfdec(ihcat[row*512 + 256 + dn]) + bfdec(h_lo[row*256 + dn]);
        float hnew = (1.f - zg)*ng + zg*hv;
        unsigned short hh = f2bf_u(hnew);
        ihcat_nxt[row*512 + 256 + dn] = hh;
        h_lo[row*256 + dn] = f2bf_u(hnew - bfdec(hh));
      }
    }
}

__global__ void reduce_kernel(const unsigned short* __restrict__ ihcat,
                              const unsigned short* __restrict__ h_lo,
                              float* __restrict__ sbuf){
  int b  = blockIdx.x / 50;
  int s0 = (blockIdx.x % 50) * 200;
  int d  = threadIdx.x;
  size_t row = (size_t)b*NNODES + s0;
  float acc = 0.f;
  for (int i=0;i<200;i++){
    acc += bfdec(ihcat[(row+i)*512 + 256 + d]) + bfdec(h_lo[(row+i)*256 + d]);
  }
  atomicAdd(&sbuf[b*DIM + d], acc);
}

__global__ __launch_bounds__(320) void head_kernel(
    const float* __restrict__ sbuf, const float* __restrict__ pt,
    const float* __restrict__ fc1w, const float* __restrict__ fc1b,
    const float* __restrict__ fc2w, const float* __restrict__ fc2b,
    const float* __restrict__ fc3w, const float* __restrict__ fc3b,
    float* __restrict__ out)
{
  __shared__ float L[4][257];
  __shared__ float T1[4][80];
  __shared__ float T2[4][80];
  __shared__ float fmx[4];
  int t = threadIdx.x;
  if (t < 256){
    for (int b=0;b<4;b++){
      float v = sbuf[b*DIM + t];
      float ll = logf(v);
      if (ll != ll) ll = 0.f;
      ll = fmaxf(ll, 0.f);
      L[b][t] = ll;
    }
  }
  __syncthreads();
  int w = t >> 6, lane = t & 63;
  if (w < 4){
    float m = -INFINITY;
    for (int i=lane;i<256;i+=64){ float v = L[w][i]; if (v != INFINITY) m = fmaxf(m, v); }
    #pragma unroll
    for (int o=32;o>=1;o>>=1) m = fmaxf(m, __shfl_xor(m, o, 64));
    if (lane==0) fmx[w] = m;
  }
  __syncthreads();
  if (t < 256){
    for (int b=0;b<4;b++) if (L[b][t] == INFINITY) L[b][t] = fmx[b];
  }
  if (t < 4) L[t][256] = pt[t];
  __syncthreads();
  if (t < 320){
    int b = t/80, i = t%80;
    float a = fc1b[i];
    for (int k=0;k<257;k++) a += L[b][k]*fc1w[i*257+k];
    T1[b][i] = leakyf(a);
  }
  __syncthreads();
  if (t < 320){
    int b = t/80, i = t%80;
    float a = fc2b[i];
    for (int k=0;k<80;k++) a += T1[b][k]*fc2w[i*80+k];
    T2[b][i] = leakyf(a);
  }
  __syncthreads();
  if (t < 40){
    int b = t/10, i = t%10;
    float a = fc3b[i];
    for (int k=0;k<80;k++) a += T2[b][k]*fc3w[i*80+k];
    out[b*10+i] = a;
  }
}

extern "C" void kernel_launch(void* const* d_in, const int* in_sizes, int n_in,
                              void* d_out, int out_size, void* d_ws, size_t ws_size,
                              hipStream_t stream) {
  const float* nodes = (const float*)d_in[0];
  const int*   edges = (const int*)d_in[1];
  const float* pt    = (const float*)d_in[2];
  const float* w_ih  = (const float*)d_in[3];
  const float* w_hh  = (const float*)d_in[4];
  const float* b_ih  = (const float*)d_in[5];
  const float* b_hh  = (const float*)d_in[6];
  const float* ew1   = (const float*)d_in[7];
  const float* eb1   = (const float*)d_in[8];
  const float* ew2   = (const float*)d_in[9];
  const float* eb2   = (const float*)d_in[10];
  const float* fc1w  = (const float*)d_in[11];
  const float* fc1b  = (const float*)d_in[12];
  const float* fc2w  = (const float*)d_in[13];
  const float* fc2b  = (const float*)d_in[14];
  const float* fc3w  = (const float*)d_in[15];
  const float* fc3b  = (const float*)d_in[16];

  const size_t HN  = (size_t)BATCH*NNODES*DIM;    // 10,240,000 (real rows)
  const size_t HNP = (size_t)MROWS*DIM;
  char* p = (char*)d_ws;
  float* sbuf = (float*)p;                        p += BATCH*DIM*4;
  unsigned short* ihcat0 = (unsigned short*)p;    p += (size_t)MROWS*512*2;  // [ib | h]
  unsigned short* ihcat1 = (unsigned short*)p;    p += (size_t)MROWS*512*2;
  unsigned short* h_lo   = (unsigned short*)p;    p += HNP*2;
  unsigned short* Zb   = (unsigned short*)p;      p += 2*HNP*2;              // z/agg scratch
  unsigned short* Sb   = (unsigned short*)p;      p += (size_t)MROWS*512*2;  // dead after w2 -> rz
  unsigned short* w1cat= (unsigned short*)p;      p += 512*256*2;
  unsigned short* w2k  = (unsigned short*)p;      p += 256*1024*2;
  unsigned short* wihk = (unsigned short*)p;      p += 768*512*2;
  unsigned short* whhk = (unsigned short*)p;      p += 768*512*2;
  unsigned short* wcomb= (unsigned short*)p;      p += 512*1024*2;
  int* off  = (int*)p;                            p += NG*(NNODES+1)*4;
  int* cur  = (int*)p;                            p += NG*NNODES*4;
  int* ssrc = (int*)p;                            p += (size_t)NG*NEDGES*4;

  unsigned short* rz_r = (unsigned short*)Sb;              // MROWS*256 u16
  unsigned short* rz_z = rz_r + (size_t)MROWS*256;         // MROWS*256 u16

  // weights
  w1cat_kernel<<<512,256,0,stream>>>(ew1, w1cat);
  w2k_kernel<<<1024,256,0,stream>>>(ew2, w2k);
  wk2_kernel<<<1536,256,0,stream>>>(w_ih, wihk);
  wk2_kernel<<<1536,256,0,stream>>>(w_hh, whhk);
  wcomb_kernel<<<2048,256,0,stream>>>(w_ih, w_hh, wcomb);

  // h0
  ihinit_kernel<<<(int)(HN/256),256,0,stream>>>(nodes, ihcat0, h_lo);

  // counting sort (CSR) of edges by dst, per stream g
  hipMemsetAsync(cur, 0, NG*NNODES*sizeof(int), stream);
  hist_kernel<<<(NG*NEDGES)/256,256,0,stream>>>(edges, cur);
  scan_kernel<<<NG,256,0,stream>>>(cur, off);
  hipMemsetAsync(cur, 0, NG*NNODES*sizeof(int), stream);
  scatter_kernel<<<(NG*NEDGES)/256,256,0,stream>>>(edges, off, cur, ssrc);

  hipMemsetAsync(sbuf, 0, BATCH*DIM*sizeof(float), stream);

  unsigned short* ih[2] = {ihcat0, ihcat1};

  for (int pass=0; pass<6; pass++){
    unsigned short* curb = ih[pass & 1];
    unsigned short* nxtb = ih[(pass+1) & 1];
    z64_kernel<<<RGRP128*8*4,256,0,stream>>>(curb, w1cat, eb1, Zb);
    aggregate_kernel<<<5000,256,0,stream>>>(Zb, ssrc, off, Sb);
    w264_kernel<<<RGRP128*8*2,256,0,stream>>>(Sb, w2k, eb2, off, curb);
    gruA_kernel<<<RGRP128*8*4,256,0,stream>>>(curb, wcomb, b_ih, b_hh, rz_r, rz_z);
    gruB_kernel<<<RGRP*8*2,256,0,stream>>>(curb, h_lo, wihk, whhk, b_ih, b_hh,
                                           rz_r, rz_z, nxtb);
  }
  reduce_kernel<<<200,256,0,stream>>>(ih[0], h_lo, sbuf);
  head_kernel<<<1,320,0,stream>>>(sbuf, pt, fc1w,fc1b,fc2w,fc2b,fc3w,fc3b,(float*)d_out);
}

// Round 3
// 1670.330 us; speedup vs baseline: 1.0317x; 1.0188x over previous
//
#include <hip/hip_runtime.h>
#include <math.h>

#define NNODES 10000
#define NEDGES 160000
#define DIM    256
#define BATCH  4
#define NG     8           // BATCH * S streams
#define MROWS  40064       // buffer row stride (40000 real rows)
#define RBLK   625         // 64-row blocks (gruB)
#define RGRP   79          // ceil(625/8)
#define RBLK128 313        // 128-row blocks (z64/w264/gruA): 313*128 = 40064
#define RGRP128 40         // ceil(313/8)

typedef __attribute__((ext_vector_type(8))) __bf16 bf16x8;
typedef __attribute__((ext_vector_type(4))) float  floatx4;
typedef __attribute__((ext_vector_type(8))) unsigned short ushort8v;

__device__ __forceinline__ float leakyf(float x){ return x > 0.f ? x : 0.01f*x; }
__device__ __forceinline__ float fsig(float x){ return 1.f/(1.f + __expf(-x)); }
__device__ __forceinline__ float ftanh(float x){ return 1.f - 2.f/(1.f + __expf(2.f*x)); }
__device__ __forceinline__ unsigned short f2bf_u(float x){
  unsigned int u = __float_as_uint(x);
  u += 0x7fffu + ((u >> 16) & 1u);
  return (unsigned short)(u >> 16);
}
__device__ __forceinline__ float bfdec(unsigned short u){
  return __uint_as_float(((unsigned int)u) << 16);
}
#define GATE_SCL 65535.f
#define GATE_INV 1.5259021896696422e-5f

#define VMCNT8 asm volatile("s_waitcnt vmcnt(8)" ::: "memory")
#define VMCNT6 asm volatile("s_waitcnt vmcnt(6)" ::: "memory")
#define VMCNT0 asm volatile("s_waitcnt vmcnt(0)" ::: "memory")
#define LGKM0  asm volatile("s_waitcnt lgkmcnt(0)" ::: "memory")
#define SBAR   __builtin_amdgcn_s_barrier()
#define SCHEDB __builtin_amdgcn_sched_barrier(0)

__device__ __forceinline__ void glds16(unsigned short* lds, const unsigned short* g){
  __builtin_amdgcn_global_load_lds(
      (const __attribute__((address_space(1))) void*)g,
      (__attribute__((address_space(3))) void*)lds, 16, 0, 0);
}

// h0: nodes -> ihcat0 h-half (hi) + h_lo
__global__ void ihinit_kernel(const float* __restrict__ nodes,
                              unsigned short* __restrict__ ihcat,
                              unsigned short* __restrict__ h_lo){
  int idx = blockIdx.x*256 + threadIdx.x;   // 40000*256
  int row = idx >> 8, d = idx & 255;
  float v = nodes[idx];
  unsigned short h = f2bf_u(v);
  ihcat[(size_t)row*512 + 256 + d] = h;
  h_lo[idx] = f2bf_u(v - bfdec(h));
}

// ---- weight prep ----
__global__ void w1cat_kernel(const float* __restrict__ ew1, unsigned short* __restrict__ o){
  int idx = blockIdx.x*256 + threadIdx.x;      // 512*256
  int n = idx >> 8, k = idx & 255;
  o[idx] = f2bf_u(ew1[(n>>8)*65536 + (n&255)*256 + k]);
}
__global__ void w2k_kernel(const float* __restrict__ ew2, unsigned short* __restrict__ o){
  int idx = blockIdx.x*256 + threadIdx.x;      // 256*1024
  int n = idx >> 10, kp = idx & 1023;
  int j = kp & 511, term = kp >> 9;
  int si = j >> 8, k = j & 255;
  float v = ew2[si*65536 + n*256 + k];
  unsigned short h = f2bf_u(v);
  o[idx] = term ? f2bf_u(v - bfdec(h)) : h;
}
// wk2[c][kp], kp in [0,512): K' = [hi | lo]
__global__ void wk2_kernel(const float* __restrict__ w, unsigned short* __restrict__ o){
  int idx = blockIdx.x*256 + threadIdx.x;      // 768*512
  int c = idx >> 9, kp = idx & 511;
  int k = kp & 255, term = kp >> 8;
  float v = w[c*256 + k];
  unsigned short h = f2bf_u(v);
  o[idx] = term ? f2bf_u(v - bfdec(h)) : h;
}
// wcomb[c][kp], c in [0,512) (r,z rows), kp: [Wih_hi|Whh_hi|Wih_lo|Whh_lo]
__global__ void wcomb_kernel(const float* __restrict__ wih, const float* __restrict__ whh,
                             unsigned short* __restrict__ o){
  int idx = blockIdx.x*256 + threadIdx.x;      // 512*1024
  int c = idx >> 10, kp = idx & 1023;
  int seg = kp >> 8, k = kp & 255;
  const float* w = (seg & 1) ? whh : wih;
  float v = w[c*256 + k];
  unsigned short h = f2bf_u(v);
  o[idx] = (seg >> 1) ? f2bf_u(v - bfdec(h)) : h;
}

// ---------------- edge sort (counting sort by dst, per stream g) ----------------
__global__ void hist_kernel(const int* __restrict__ edges, int* __restrict__ cnt){
  int idx = blockIdx.x*256 + threadIdx.x;
  if (idx < NG*NEDGES){
    int g = idx / NEDGES, e = idx - g*NEDGES;
    int d = edges[((size_t)g*NEDGES + e)*2];
    atomicAdd(&cnt[g*NNODES + d], 1);
  }
}

__global__ __launch_bounds__(256) void scan_kernel(const int* __restrict__ cnt, int* __restrict__ off){
  __shared__ int sc[256];
  int g = blockIdx.x, t = threadIdx.x;
  int base = 0;
  for (int c=0;c<40;c++){
    int i = c*256 + t;
    int v = (i < NNODES) ? cnt[g*NNODES + i] : 0;
    __syncthreads();
    sc[t] = v;
    __syncthreads();
    for (int o=1;o<256;o<<=1){
      int u = (t>=o) ? sc[t-o] : 0;
      __syncthreads();
      sc[t] += u;
      __syncthreads();
    }
    if (i < NNODES) off[g*(NNODES+1) + i] = base + sc[t] - v;
    base += sc[255];
  }
  if (t == 0) off[g*(NNODES+1) + NNODES] = base;
}

__global__ void scatter_kernel(const int* __restrict__ edges, const int* __restrict__ off,
                               int* __restrict__ cur, int* __restrict__ ssrc){
  int idx = blockIdx.x*256 + threadIdx.x;
  if (idx < NG*NEDGES){
    int g = idx / NEDGES, e = idx - g*NEDGES;
    const int* ep = &edges[((size_t)g*NEDGES + e)*2];
    int d = ep[0], s = ep[1];
    int pos = off[g*(NNODES+1) + d] + atomicAdd(&cur[g*NNODES + d], 1);
    ssrc[g*NEDGES + pos] = s;
  }
}

// ====== 128x128 counted-vmcnt pipelined MFMA core (T4) ======
// Double-buffered LDS (buf b at lds + b*16384: A 128x64 at +0, B at +8192).
// Per step: issue next tile's 8 global_load_lds, wait vmcnt(8) (current tile
// landed, next stays in flight), raw s_barrier, ds_read+MFMA, lgkmcnt(0),
// raw s_barrier. Compute order identical to prior versions -> bit-identical.
template<int KP, int RS, int KM>
__device__ __forceinline__ void mm128_core(
    const unsigned short* __restrict__ Ab, const unsigned short* __restrict__ Wb,
    unsigned short* lds, floatx4 (&acc)[4][4])
{
  const int t = threadIdx.x;
  const int w = t >> 6, lane = t & 63;
  const int q = lane >> 4, col = lane & 15;
  const int wr = (w >> 1) * 64;
  const int wc = (w & 1) * 64;
  const int sr = t >> 3;
  const int sk = ((t & 7) ^ (sr & 7)) * 8;

  auto STAGE = [&](int kb, int buf){
    unsigned short* Al = lds + buf*16384;
    unsigned short* Bl = Al + 8192;
    #pragma unroll
    for (int i=0;i<4;i++){
      int r = i*32 + sr;
      glds16(&Al[i*2048 + w*512], &Ab[(size_t)r*RS + ((kb + sk) & KM)]);
      glds16(&Bl[i*2048 + w*512], &Wb[(size_t)r*KP + kb + sk]);
    }
  };

  STAGE(0, 0);
  int cur = 0;
  #pragma unroll
  for (int kb = 0; kb < KP; kb += 64){
    if (kb + 64 < KP){
      STAGE(kb + 64, cur^1);
      VMCNT8;
    } else {
      VMCNT0;
    }
    SBAR; SCHEDB;
    const unsigned short* Al = lds + cur*16384;
    const unsigned short* Bl = Al + 8192;
    #pragma unroll
    for (int ks2=0; ks2<2; ks2++){
      bf16x8 a[4], bf[4];
      #pragma unroll
      for (int mi=0;mi<4;mi++){
        int r = wr + mi*16 + col;
        int j = (ks2*4 + q) ^ (r & 7);
        a[mi] = *(const bf16x8*)&Al[r*64 + j*8];
      }
      #pragma unroll
      for (int ni=0;ni<4;ni++){
        int r = wc + ni*16 + col;
        int j = (ks2*4 + q) ^ (r & 7);
        bf[ni] = *(const bf16x8*)&Bl[r*64 + j*8];
      }
      #pragma unroll
      for (int mi=0;mi<4;mi++)
        #pragma unroll
        for (int ni=0;ni<4;ni++)
          acc[mi][ni] = __builtin_amdgcn_mfma_f32_16x16x32_bf16(a[mi], bf[ni], acc[mi][ni], 0,0,0);
    }
    SCHEDB; LGKM0; SBAR;
    cur ^= 1;
  }
}

// ====== fused dual-GEMM 64x128 counted-vmcnt pipelined core (gruB) ======
// 16 steps: s=0..7 accumulate A1@W1 into ai, s=8..15 A2@W2 into ah.
// A col wraps &255 (hi/lo weight split vs single-bf16 activation).
// Per-accumulator MFMA order identical to two sequential calls.
__device__ __forceinline__ void mm64x2_core(
    const unsigned short* __restrict__ A1, const unsigned short* __restrict__ W1,
    const unsigned short* __restrict__ A2, const unsigned short* __restrict__ W2,
    unsigned short* lds, floatx4 (&ai)[4][2], floatx4 (&ah)[4][2])
{
  const int t = threadIdx.x;
  const int w = t >> 6, lane = t & 63;
  const int q = lane >> 4, col = lane & 15;
  const int wc = w*32;
  const int sr = t >> 3;
  const int sk = ((t & 7) ^ (sr & 7)) * 8;

  auto STAGE = [&](int s, int buf){
    const unsigned short* A = (s < 8) ? A1 : A2;
    const unsigned short* W = (s < 8) ? W1 : W2;
    int kb = (s & 7) * 64;
    unsigned short* Al = lds + buf*12288;
    unsigned short* Bl = Al + 4096;
    #pragma unroll
    for (int i=0;i<2;i++){
      int r = i*32 + sr;
      glds16(&Al[i*2048 + w*512], &A[(size_t)r*512 + ((kb + sk) & 255)]);
    }
    #pragma unroll
    for (int i=0;i<4;i++){
      int r = i*32 + sr;
      glds16(&Bl[i*2048 + w*512], &W[(size_t)r*512 + kb + sk]);
    }
  };

  STAGE(0, 0);
  int cur = 0;
  #pragma unroll
  for (int s = 0; s < 16; s++){
    if (s < 15){
      STAGE(s + 1, cur^1);
      VMCNT6;
    } else {
      VMCNT0;
    }
    SBAR; SCHEDB;
    const unsigned short* Al = lds + cur*12288;
    const unsigned short* Bl = Al + 4096;
    #pragma unroll
    for (int ks2=0; ks2<2; ks2++){
      bf16x8 a[4], bf[2];
      #pragma unroll
      for (int mi=0;mi<4;mi++){
        int r = mi*16 + col;
        int j = (ks2*4 + q) ^ (r & 7);
        a[mi] = *(const bf16x8*)&Al[r*64 + j*8];
      }
      #pragma unroll
      for (int ni=0;ni<2;ni++){
        int r = wc + ni*16 + col;
        int j = (ks2*4 + q) ^ (r & 7);
        bf[ni] = *(const bf16x8*)&Bl[r*64 + j*8];
      }
      if (s < 8){
        #pragma unroll
        for (int mi=0;mi<4;mi++)
          #pragma unroll
          for (int ni=0;ni<2;ni++)
            ai[mi][ni] = __builtin_amdgcn_mfma_f32_16x16x32_bf16(a[mi], bf[ni], ai[mi][ni], 0,0,0);
      } else {
        #pragma unroll
        for (int mi=0;mi<4;mi++)
          #pragma unroll
          for (int ni=0;ni<2;ni++)
            ah[mi][ni] = __builtin_amdgcn_mfma_f32_16x16x32_bf16(a[mi], bf[ni], ah[mi][ni], 0,0,0);
      }
    }
    SCHEDB; LGKM0; SBAR;
    cur ^= 1;
  }
}

// XCD-aligned 1-D grid decode: row-block rb lands on XCD rb%8.
#define XDECODE(NCOL) \
  const int bid_ = blockIdx.x; \
  const int rb_ = ((bid_ >> 3) / NCOL) * 8 + (bid_ & 7); \
  const int colb_ = (bid_ >> 3) % NCOL; \
  if (rb_ >= RBLK) return;

#define XDECODE128(NCOL) \
  const int bid_ = blockIdx.x; \
  const int rb_ = ((bid_ >> 3) / NCOL) * 8 + (bid_ & 7); \
  const int colb_ = (bid_ >> 3) % NCOL; \
  if (rb_ >= RBLK128) return;

#define MMPRO128 \
  const int t = threadIdx.x, w = t >> 6, lane = t & 63; \
  const int q = lane >> 4, col = lane & 15; \
  const int wrq = (w >> 1) * 64, wcq = (w & 1) * 64; \
  floatx4 acc[4][4]; \
  _Pragma("unroll") for (int mi=0;mi<4;mi++) _Pragma("unroll") for (int ni=0;ni<4;ni++) \
    acc[mi][ni] = (floatx4){0.f,0.f,0.f,0.f};

// ---- Z = leaky(h @ W1cat^T + b1): NCOL=4; h read from ihcat h-half ----
__global__ __launch_bounds__(256) void z64_kernel(
    const unsigned short* __restrict__ ihcat, const unsigned short* __restrict__ w1cat,
    const float* __restrict__ eb1, unsigned short* __restrict__ Z)
{
  __shared__ unsigned short lds[32768];
  XDECODE128(4)
  const int row0 = rb_*128, col0 = colb_*128;
  MMPRO128
  mm128_core<256,512,255>(ihcat + (size_t)row0*512 + 256, w1cat + (size_t)col0*256, lds, acc);

  #pragma unroll
  for (int ni=0;ni<4;ni++){
    int n = col0 + wcq + ni*16 + col;
    int si = n >> 8, cz = n & 255;
    float bb = eb1[si*256 + cz];
    unsigned short* zp = Z + (size_t)si*MROWS*256 + cz;
    #pragma unroll
    for (int mi=0;mi<4;mi++)
      #pragma unroll
      for (int rr=0;rr<4;rr++){
        int row = row0 + wrq + mi*16 + q*4 + rr;
        zp[(size_t)row*256] = f2bf_u(leakyf(acc[mi][ni][rr] + bb));
      }
  }
}

// ---- CSR aggregate, XCD-pinned to stream: g = bid & 7 ----
// Paired-row gather: lanes 0-31 process node d, lanes 32-63 node d+1.
// Unroll-8: sums as two sequential 4-groups (FP order == 4-unrolled loop).
__global__ __launch_bounds__(256) void aggregate_kernel(
    const unsigned short* __restrict__ Z, const int* __restrict__ ssrc,
    const int* __restrict__ off, unsigned short* __restrict__ Sb)
{
  const int bid = blockIdx.x;          // 5000
  const int g = bid & 7;
  const int dgrp = bid >> 3;           // 0..624
  const int b = g >> 1, si = g & 1;
  const int w = threadIdx.x >> 6, lane = threadIdx.x & 63;
  const int half = lane >> 5, c = lane & 31;
  const unsigned short* zb = Z + ((size_t)si*MROWS + b*10000)*256 + c*8;
  const int* sp = ssrc + (size_t)g*NEDGES;
  const int* offg = off + g*(NNODES+1);

  #pragma unroll
  for (int p=0;p<2;p++){
    const int d = dgrp*16 + w*4 + p*2 + half;
    int j = offg[d];
    const int j1 = offg[d+1];
    float a0=0.f,a1=0.f,a2=0.f,a3=0.f,a4=0.f,a5=0.f,a6=0.f,a7=0.f;
    for (; j+8 <= j1; j+=8){
      int s[8];
      #pragma unroll
      for (int e=0;e<8;e++) s[e] = sp[j+e];
      ushort8v u[8];
      #pragma unroll
      for (int e=0;e<8;e++) u[e] = *(const ushort8v*)&zb[(size_t)s[e]*256];
      a0 += bfdec(u[0][0])+bfdec(u[1][0])+bfdec(u[2][0])+bfdec(u[3][0]);
      a1 += bfdec(u[0][1])+bfdec(u[1][1])+bfdec(u[2][1])+bfdec(u[3][1]);
      a2 += bfdec(u[0][2])+bfdec(u[1][2])+bfdec(u[2][2])+bfdec(u[3][2]);
      a3 += bfdec(u[0][3])+bfdec(u[1][3])+bfdec(u[2][3])+bfdec(u[3][3]);
      a4 += bfdec(u[0][4])+bfdec(u[1][4])+bfdec(u[2][4])+bfdec(u[3][4]);
      a5 += bfdec(u[0][5])+bfdec(u[1][5])+bfdec(u[2][5])+bfdec(u[3][5]);
      a6 += bfdec(u[0][6])+bfdec(u[1][6])+bfdec(u[2][6])+bfdec(u[3][6]);
      a7 += bfdec(u[0][7])+bfdec(u[1][7])+bfdec(u[2][7])+bfdec(u[3][7]);
      a0 += bfdec(u[4][0])+bfdec(u[5][0])+bfdec(u[6][0])+bfdec(u[7][0]);
      a1 += bfdec(u[4][1])+bfdec(u[5][1])+bfdec(u[6][1])+bfdec(u[7][1]);
      a2 += bfdec(u[4][2])+bfdec(u[5][2])+bfdec(u[6][2])+bfdec(u[7][2]);
      a3 += bfdec(u[4][3])+bfdec(u[5][3])+bfdec(u[6][3])+bfdec(u[7][3]);
      a4 += bfdec(u[4][4])+bfdec(u[5][4])+bfdec(u[6][4])+bfdec(u[7][4]);
      a5 += bfdec(u[4][5])+bfdec(u[5][5])+bfdec(u[6][5])+bfdec(u[7][5]);
      a6 += bfdec(u[4][6])+bfdec(u[5][6])+bfdec(u[6][6])+bfdec(u[7][6]);
      a7 += bfdec(u[4][7])+bfdec(u[5][7])+bfdec(u[6][7])+bfdec(u[7][7]);
    }
    for (; j+4 <= j1; j+=4){
      int s0=sp[j], s1=sp[j+1], s2=sp[j+2], s3=sp[j+3];
      ushort8v u0 = *(const ushort8v*)&zb[(size_t)s0*256];
      ushort8v u1 = *(const ushort8v*)&zb[(size_t)s1*256];
      ushort8v u2 = *(const ushort8v*)&zb[(size_t)s2*256];
      ushort8v u3 = *(const ushort8v*)&zb[(size_t)s3*256];
      a0 += bfdec(u0[0])+bfdec(u1[0])+bfdec(u2[0])+bfdec(u3[0]);
      a1 += bfdec(u0[1])+bfdec(u1[1])+bfdec(u2[1])+bfdec(u3[1]);
      a2 += bfdec(u0[2])+bfdec(u1[2])+bfdec(u2[2])+bfdec(u3[2]);
      a3 += bfdec(u0[3])+bfdec(u1[3])+bfdec(u2[3])+bfdec(u3[3]);
      a4 += bfdec(u0[4])+bfdec(u1[4])+bfdec(u2[4])+bfdec(u3[4]);
      a5 += bfdec(u0[5])+bfdec(u1[5])+bfdec(u2[5])+bfdec(u3[5]);
      a6 += bfdec(u0[6])+bfdec(u1[6])+bfdec(u2[6])+bfdec(u3[6]);
      a7 += bfdec(u0[7])+bfdec(u1[7])+bfdec(u2[7])+bfdec(u3[7]);
    }
    for (; j < j1; j++){
      ushort8v u = *(const ushort8v*)&zb[(size_t)sp[j]*256];
      a0+=bfdec(u[0]); a1+=bfdec(u[1]); a2+=bfdec(u[2]); a3+=bfdec(u[3]);
      a4+=bfdec(u[4]); a5+=bfdec(u[5]); a6+=bfdec(u[6]); a7+=bfdec(u[7]);
    }
    size_t so = (size_t)(b*10000 + d)*512 + si*256 + c*8;
    ushort8v hv;
    hv[0]=f2bf_u(a0); hv[1]=f2bf_u(a1); hv[2]=f2bf_u(a2); hv[3]=f2bf_u(a3);
    hv[4]=f2bf_u(a4); hv[5]=f2bf_u(a5); hv[6]=f2bf_u(a6); hv[7]=f2bf_u(a7);
    *(ushort8v*)&Sb[so] = hv;
  }
}

// ---- ihcat.ib = S @ W2k^T (2-term K'=1024) + deg.b2: NCOL=2 ----
__global__ __launch_bounds__(256) void w264_kernel(
    const unsigned short* __restrict__ Sb, const unsigned short* __restrict__ w2k,
    const float* __restrict__ eb2, const int* __restrict__ off,
    unsigned short* __restrict__ ihcat)
{
  __shared__ unsigned short lds[32768];
  XDECODE128(2)
  const int row0 = rb_*128, col0 = colb_*128;
  MMPRO128
  mm128_core<1024,512,511>(Sb + (size_t)row0*512, w2k + (size_t)col0*1024, lds, acc);

  float b20[4], b21[4];
  #pragma unroll
  for (int ni=0;ni<4;ni++){
    int n = col0 + wcq + ni*16 + col;
    b20[ni] = eb2[n];
    b21[ni] = eb2[256 + n];
  }
  #pragma unroll
  for (int mi=0;mi<4;mi++)
    #pragma unroll
    for (int rr=0;rr<4;rr++){
      int row = row0 + wrq + mi*16 + q*4 + rr;
      int rw = (row < 40000) ? row : 39999;   // guard padding rows (off lookup only)
      int b = rw / 10000, d = rw - b*10000;
      int o0 = (b*2)*(NNODES+1) + d;
      int o1 = (b*2+1)*(NNODES+1) + d;
      float dg0 = (float)(off[o0+1] - off[o0]);
      float dg1 = (float)(off[o1+1] - off[o1]);
      #pragma unroll
      for (int ni=0;ni<4;ni++){
        int n = col0 + wcq + ni*16 + col;
        ihcat[(size_t)row*512 + n] = f2bf_u(acc[mi][ni][rr] + dg0*b20[ni] + dg1*b21[ni]);
      }
    }
}

// ---- gruA: combined r,z GEMM -> u16 gates. NCOL=4 ----
__global__ __launch_bounds__(256) void gruA_kernel(
    const unsigned short* __restrict__ ihcat, const unsigned short* __restrict__ wcomb,
    const float* __restrict__ b_ih, const float* __restrict__ b_hh,
    unsigned short* __restrict__ rz_r, unsigned short* __restrict__ rz_z)
{
  __shared__ unsigned short lds[32768];
  XDECODE128(4)
  const int row0 = rb_*128, col0 = colb_*128;
  MMPRO128
  mm128_core<1024,512,511>(ihcat + (size_t)row0*512, wcomb + (size_t)col0*1024, lds, acc);

  float bb[4];
  #pragma unroll
  for (int ni=0;ni<4;ni++){
    int n = col0 + wcq + ni*16 + col;
    bb[ni] = b_ih[n] + b_hh[n];
  }
  unsigned short* dst = (col0 < 256) ? rz_r : rz_z;
  const int cbase = (col0 & 255) + wcq;
  #pragma unroll
  for (int mi=0;mi<4;mi++)
    #pragma unroll
    for (int rr=0;rr<4;rr++){
      size_t row = (size_t)(row0 + wrq + mi*16 + q*4 + rr);
      #pragma unroll
      for (int ni=0;ni<4;ni++){
        float v = fsig(acc[mi][ni][rr] + bb[ni]);
        dst[row*256 + cbase + ni*16 + col] = (unsigned short)(v*GATE_SCL + 0.5f);
      }
    }
}

// ---- gruB: n gate + GRU update. NCOL=2. Writes ihcat_nxt h-half + h_lo ----
__global__ __launch_bounds__(256) void gruB_kernel(
    const unsigned short* __restrict__ ihcat, unsigned short* __restrict__ h_lo,
    const unsigned short* __restrict__ wihk, const unsigned short* __restrict__ whhk,
    const float* __restrict__ b_ih, const float* __restrict__ b_hh,
    const unsigned short* __restrict__ rz_r, const unsigned short* __restrict__ rz_z,
    unsigned short* __restrict__ ihcat_nxt)
{
  __shared__ unsigned short lds[24576];
  XDECODE(2)
  const int row0 = rb_*64, dcol0 = colb_*128;   // n-gate W cols = 512 + dcol0
  const int t = threadIdx.x, w = t >> 6, lane = t & 63;
  const int q = lane >> 4, col = lane & 15;
  const int wc = w*32;

  floatx4 ai[4][2], ah[4][2];
  #pragma unroll
  for (int mi=0;mi<4;mi++)
    #pragma unroll
    for (int ni=0;ni<2;ni++){ ai[mi][ni] = (floatx4){0.f,0.f,0.f,0.f}; ah[mi][ni] = (floatx4){0.f,0.f,0.f,0.f}; }

  mm64x2_core(ihcat + (size_t)row0*512,       wihk + (size_t)(512 + dcol0)*512,
              ihcat + (size_t)row0*512 + 256, whhk + (size_t)(512 + dcol0)*512,
              lds, ai, ah);

  float bi[2], bh[2];
  #pragma unroll
  for (int ni=0;ni<2;ni++){
    int n = 512 + dcol0 + wc + ni*16 + col;
    bi[ni] = b_ih[n]; bh[ni] = b_hh[n];
  }
  #pragma unroll
  for (int mi=0;mi<4;mi++)
    #pragma unroll
    for (int rr=0;rr<4;rr++){
      size_t row = (size_t)(row0 + mi*16 + q*4 + rr);
      #pragma unroll
      for (int ni=0;ni<2;ni++){
        int dn = dcol0 + wc + ni*16 + col;
        float rg = (float)rz_r[row*256 + dn] * GATE_INV;
        float zg = (float)rz_z[row*256 + dn] * GATE_INV;
        float ng = ftanh(ai[mi][ni][rr] + bi[ni] + rg*(ah[mi][ni][rr] + bh[ni]));
        float hv = bfdec(ihcat[row*512 + 256 + dn]) + bfdec(h_lo[row*256 + dn]);
        float hnew = (1.f - zg)*ng + zg*hv;
        unsigned short hh = f2bf_u(hnew);
        ihcat_nxt[row*512 + 256 + dn] = hh;
        h_lo[row*256 + dn] = f2bf_u(hnew - bfdec(hh));
      }
    }
}

__global__ void reduce_kernel(const unsigned short* __restrict__ ihcat,
                              const unsigned short* __restrict__ h_lo,
                              float* __restrict__ sbuf){
  int b  = blockIdx.x / 50;
  int s0 = (blockIdx.x % 50) * 200;
  int d  = threadIdx.x;
  size_t row = (size_t)b*NNODES + s0;
  float acc = 0.f;
  for (int i=0;i<200;i++){
    acc += bfdec(ihcat[(row+i)*512 + 256 + d]) + bfdec(h_lo[(row+i)*256 + d]);
  }
  atomicAdd(&sbuf[b*DIM + d], acc);
}

__global__ __launch_bounds__(320) void head_kernel(
    const float* __restrict__ sbuf, const float* __restrict__ pt,
    const float* __restrict__ fc1w, const float* __restrict__ fc1b,
    const float* __restrict__ fc2w, const float* __restrict__ fc2b,
    const float* __restrict__ fc3w, const float* __restrict__ fc3b,
    float* __restrict__ out)
{
  __shared__ float L[4][257];
  __shared__ float T1[4][80];
  __shared__ float T2[4][80];
  __shared__ float fmx[4];
  int t = threadIdx.x;
  if (t < 256){
    for (int b=0;b<4;b++){
      float v = sbuf[b*DIM + t];
      float ll = logf(v);
      if (ll != ll) ll = 0.f;
      ll = fmaxf(ll, 0.f);
      L[b][t] = ll;
    }
  }
  __syncthreads();
  int w = t >> 6, lane = t & 63;
  if (w < 4){
    float m = -INFINITY;
    for (int i=lane;i<256;i+=64){ float v = L[w][i]; if (v != INFINITY) m = fmaxf(m, v); }
    #pragma unroll
    for (int o=32;o>=1;o>>=1) m = fmaxf(m, __shfl_xor(m, o, 64));
    if (lane==0) fmx[w] = m;
  }
  __syncthreads();
  if (t < 256){
    for (int b=0;b<4;b++) if (L[b][t] == INFINITY) L[b][t] = fmx[b];
  }
  if (t < 4) L[t][256] = pt[t];
  __syncthreads();
  if (t < 320){
    int b = t/80, i = t%80;
    float a = fc1b[i];
    for (int k=0;k<257;k++) a += L[b][k]*fc1w[i*257+k];
    T1[b][i] = leakyf(a);
  }
  __syncthreads();
  if (t < 320){
    int b = t/80, i = t%80;
    float a = fc2b[i];
    for (int k=0;k<80;k++) a += T1[b][k]*fc2w[i*80+k];
    T2[b][i] = leakyf(a);
  }
  __syncthreads();
  if (t < 40){
    int b = t/10, i = t%10;
    float a = fc3b[i];
    for (int k=0;k<80;k++) a += T2[b][k]*fc3w[i*80+k];
    out[b*10+i] = a;
  }
}

extern "C" void kernel_launch(void* const* d_in, const int* in_sizes, int n_in,
                              void* d_out, int out_size, void* d_ws, size_t ws_size,
                              hipStream_t stream) {
  const float* nodes = (const float*)d_in[0];
  const int*   edges = (const int*)d_in[1];
  const float* pt    = (const float*)d_in[2];
  const float* w_ih  = (const float*)d_in[3];
  const float* w_hh  = (const float*)d_in[4];
  const float* b_ih  = (const float*)d_in[5];
  const float* b_hh  = (const float*)d_in[6];
  const float* ew1   = (const float*)d_in[7];
  const float* eb1   = (const float*)d_in[8];
  const float* ew2   = (const float*)d_in[9];
  const float* eb2   = (const float*)d_in[10];
  const float* fc1w  = (const float*)d_in[11];
  const float* fc1b  = (const float*)d_in[12];
  const float* fc2w  = (const float*)d_in[13];
  const float* fc2b  = (const float*)d_in[14];
  const float* fc3w  = (const float*)d_in[15];
  const float* fc3b  = (const float*)d_in[16];

  const size_t HN  = (size_t)BATCH*NNODES*DIM;    // 10,240,000 (real rows)
  const size_t HNP = (size_t)MROWS*DIM;
  char* p = (char*)d_ws;
  float* sbuf = (float*)p;                        p += BATCH*DIM*4;
  unsigned short* ihcat0 = (unsigned short*)p;    p += (size_t)MROWS*512*2;  // [ib | h]
  unsigned short* ihcat1 = (unsigned short*)p;    p += (size_t)MROWS*512*2;
  unsigned short* h_lo   = (unsigned short*)p;    p += HNP*2;
  unsigned short* Zb   = (unsigned short*)p;      p += 2*HNP*2;              // z/agg scratch
  unsigned short* Sb   = (unsigned short*)p;      p += (size_t)MROWS*512*2;  // dead after w2 -> rz
  unsigned short* w1cat= (unsigned short*)p;      p += 512*256*2;
  unsigned short* w2k  = (unsigned short*)p;      p += 256*1024*2;
  unsigned short* wihk = (unsigned short*)p;      p += 768*512*2;
  unsigned short* whhk = (unsigned short*)p;      p += 768*512*2;
  unsigned short* wcomb= (unsigned short*)p;      p += 512*1024*2;
  int* off  = (int*)p;                            p += NG*(NNODES+1)*4;
  int* cur  = (int*)p;                            p += NG*NNODES*4;
  int* ssrc = (int*)p;                            p += (size_t)NG*NEDGES*4;

  unsigned short* rz_r = (unsigned short*)Sb;              // MROWS*256 u16
  unsigned short* rz_z = rz_r + (size_t)MROWS*256;         // MROWS*256 u16

  // weights
  w1cat_kernel<<<512,256,0,stream>>>(ew1, w1cat);
  w2k_kernel<<<1024,256,0,stream>>>(ew2, w2k);
  wk2_kernel<<<1536,256,0,stream>>>(w_ih, wihk);
  wk2_kernel<<<1536,256,0,stream>>>(w_hh, whhk);
  wcomb_kernel<<<2048,256,0,stream>>>(w_ih, w_hh, wcomb);

  // h0
  ihinit_kernel<<<(int)(HN/256),256,0,stream>>>(nodes, ihcat0, h_lo);

  // counting sort (CSR) of edges by dst, per stream g
  hipMemsetAsync(cur, 0, NG*NNODES*sizeof(int), stream);
  hist_kernel<<<(NG*NEDGES)/256,256,0,stream>>>(edges, cur);
  scan_kernel<<<NG,256,0,stream>>>(cur, off);
  hipMemsetAsync(cur, 0, NG*NNODES*sizeof(int), stream);
  scatter_kernel<<<(NG*NEDGES)/256,256,0,stream>>>(edges, off, cur, ssrc);

  hipMemsetAsync(sbuf, 0, BATCH*DIM*sizeof(float), stream);

  unsigned short* ih[2] = {ihcat0, ihcat1};

  for (int pass=0; pass<6; pass++){
    unsigned short* curb = ih[pass & 1];
    unsigned short* nxtb = ih[(pass+1) & 1];
    z64_kernel<<<RGRP128*8*4,256,0,stream>>>(curb, w1cat, eb1, Zb);
    aggregate_kernel<<<5000,256,0,stream>>>(Zb, ssrc, off, Sb);
    w264_kernel<<<RGRP128*8*2,256,0,stream>>>(Sb, w2k, eb2, off, curb);
    gruA_kernel<<<RGRP128*8*4,256,0,stream>>>(curb, wcomb, b_ih, b_hh, rz_r, rz_z);
    gruB_kernel<<<RGRP*8*2,256,0,stream>>>(curb, h_lo, wihk, whhk, b_ih, b_hh,
                                           rz_r, rz_z, nxtb);
  }
  reduce_kernel<<<200,256,0,stream>>>(ih[0], h_lo, sbuf);
  head_kernel<<<1,320,0,stream>>>(sbuf, pt, fc1w,fc1b,fc2w,fc2b,fc3w,fc3b,(float*)d_out);
}

// Round 4
// 1566.981 us; speedup vs baseline: 1.0997x; 1.0660x over previous
//
#include <hip/hip_runtime.h>
#include <math.h>

#define NNODES 10000
#define NEDGES 160000
#define DIM    256
#define BATCH  4
#define NG     8           // BATCH * S streams
#define MROWS  40064       // buffer row stride (40000 real rows)
#define RBLK   625         // 64-row blocks (gruB)
#define RGRP   79          // ceil(625/8)
#define RBLK128 313        // 128-row blocks (z64/w264/gruA): 313*128 = 40064
#define RGRP128 40         // ceil(313/8)

typedef __attribute__((ext_vector_type(8))) __bf16 bf16x8;
typedef __attribute__((ext_vector_type(4))) float  floatx4;
typedef __attribute__((ext_vector_type(8))) unsigned short ushort8v;

__device__ __forceinline__ float leakyf(float x){ return x > 0.f ? x : 0.01f*x; }
__device__ __forceinline__ float fsig(float x){ return 1.f/(1.f + __expf(-x)); }
__device__ __forceinline__ float ftanh(float x){ return 1.f - 2.f/(1.f + __expf(2.f*x)); }
__device__ __forceinline__ unsigned short f2bf_u(float x){
  unsigned int u = __float_as_uint(x);
  u += 0x7fffu + ((u >> 16) & 1u);
  return (unsigned short)(u >> 16);
}
__device__ __forceinline__ float bfdec(unsigned short u){
  return __uint_as_float(((unsigned int)u) << 16);
}
#define GATE_SCL 65535.f
#define GATE_INV 1.5259021896696422e-5f

#define VMCNT4 asm volatile("s_waitcnt vmcnt(4)" ::: "memory")
#define VMCNT3 asm volatile("s_waitcnt vmcnt(3)" ::: "memory")
#define VMCNT0 asm volatile("s_waitcnt vmcnt(0)" ::: "memory")
#define LGKM0  asm volatile("s_waitcnt lgkmcnt(0)" ::: "memory")
#define SBAR   __builtin_amdgcn_s_barrier()
#define SCHEDB __builtin_amdgcn_sched_barrier(0)

__device__ __forceinline__ void glds16(unsigned short* lds, const unsigned short* g){
  __builtin_amdgcn_global_load_lds(
      (const __attribute__((address_space(1))) void*)g,
      (__attribute__((address_space(3))) void*)lds, 16, 0, 0);
}

// h0: nodes -> ihcat0 h-half (hi) + h_lo
__global__ void ihinit_kernel(const float* __restrict__ nodes,
                              unsigned short* __restrict__ ihcat,
                              unsigned short* __restrict__ h_lo){
  int idx = blockIdx.x*256 + threadIdx.x;   // 40000*256
  int row = idx >> 8, d = idx & 255;
  float v = nodes[idx];
  unsigned short h = f2bf_u(v);
  ihcat[(size_t)row*512 + 256 + d] = h;
  h_lo[idx] = f2bf_u(v - bfdec(h));
}

// ---- weight prep ----
__global__ void w1cat_kernel(const float* __restrict__ ew1, unsigned short* __restrict__ o){
  int idx = blockIdx.x*256 + threadIdx.x;      // 512*256
  int n = idx >> 8, k = idx & 255;
  o[idx] = f2bf_u(ew1[(n>>8)*65536 + (n&255)*256 + k]);
}
__global__ void w2k_kernel(const float* __restrict__ ew2, unsigned short* __restrict__ o){
  int idx = blockIdx.x*256 + threadIdx.x;      // 256*1024
  int n = idx >> 10, kp = idx & 1023;
  int j = kp & 511, term = kp >> 9;
  int si = j >> 8, k = j & 255;
  float v = ew2[si*65536 + n*256 + k];
  unsigned short h = f2bf_u(v);
  o[idx] = term ? f2bf_u(v - bfdec(h)) : h;
}
// wk2[c][kp], kp in [0,512): K' = [hi | lo]
__global__ void wk2_kernel(const float* __restrict__ w, unsigned short* __restrict__ o){
  int idx = blockIdx.x*256 + threadIdx.x;      // 768*512
  int c = idx >> 9, kp = idx & 511;
  int k = kp & 255, term = kp >> 8;
  float v = w[c*256 + k];
  unsigned short h = f2bf_u(v);
  o[idx] = term ? f2bf_u(v - bfdec(h)) : h;
}
// wcomb[c][kp], c in [0,512) (r,z rows), kp: [Wih_hi|Whh_hi|Wih_lo|Whh_lo]
__global__ void wcomb_kernel(const float* __restrict__ wih, const float* __restrict__ whh,
                             unsigned short* __restrict__ o){
  int idx = blockIdx.x*256 + threadIdx.x;      // 512*1024
  int c = idx >> 10, kp = idx & 1023;
  int seg = kp >> 8, k = kp & 255;
  const float* w = (seg & 1) ? whh : wih;
  float v = w[c*256 + k];
  unsigned short h = f2bf_u(v);
  o[idx] = (seg >> 1) ? f2bf_u(v - bfdec(h)) : h;
}

// ---------------- edge sort (counting sort by dst, per stream g) ----------------
__global__ void hist_kernel(const int* __restrict__ edges, int* __restrict__ cnt){
  int idx = blockIdx.x*256 + threadIdx.x;
  if (idx < NG*NEDGES){
    int g = idx / NEDGES, e = idx - g*NEDGES;
    int d = edges[((size_t)g*NEDGES + e)*2];
    atomicAdd(&cnt[g*NNODES + d], 1);
  }
}

__global__ __launch_bounds__(256) void scan_kernel(const int* __restrict__ cnt, int* __restrict__ off){
  __shared__ int sc[256];
  int g = blockIdx.x, t = threadIdx.x;
  int base = 0;
  for (int c=0;c<40;c++){
    int i = c*256 + t;
    int v = (i < NNODES) ? cnt[g*NNODES + i] : 0;
    __syncthreads();
    sc[t] = v;
    __syncthreads();
    for (int o=1;o<256;o<<=1){
      int u = (t>=o) ? sc[t-o] : 0;
      __syncthreads();
      sc[t] += u;
      __syncthreads();
    }
    if (i < NNODES) off[g*(NNODES+1) + i] = base + sc[t] - v;
    base += sc[255];
  }
  if (t == 0) off[g*(NNODES+1) + NNODES] = base;
}

__global__ void scatter_kernel(const int* __restrict__ edges, const int* __restrict__ off,
                               int* __restrict__ cur, int* __restrict__ ssrc){
  int idx = blockIdx.x*256 + threadIdx.x;
  if (idx < NG*NEDGES){
    int g = idx / NEDGES, e = idx - g*NEDGES;
    const int* ep = &edges[((size_t)g*NEDGES + e)*2];
    int d = ep[0], s = ep[1];
    int pos = off[g*(NNODES+1) + d] + atomicAdd(&cur[g*NNODES + d], 1);
    ssrc[g*NEDGES + pos] = s;
  }
}

// ====== 128x128 8-wave counted-vmcnt pipelined MFMA core ======
// 512 threads. Wave w: rows (w>>2)*64, cols (w&3)*32 -> acc[4][2].
// LDS layout identical to 4-wave version (A 128x64 at +0, B at +8192 per buf);
// staging re-divided: 4 glds16/thread/step -> vmcnt(4) 1-deep prefetch.
// Per-output K-accumulation order unchanged -> bit-identical.
template<int KP, int RS, int KM>
__device__ __forceinline__ void mm128_core(
    const unsigned short* __restrict__ Ab, const unsigned short* __restrict__ Wb,
    unsigned short* lds, floatx4 (&acc)[4][2])
{
  const int t = threadIdx.x;
  const int w = t >> 6, lane = t & 63;
  const int q = lane >> 4, col = lane & 15;
  const int wr = (w >> 2) * 64;
  const int wc = (w & 3) * 32;
  const int sr = t >> 3;                 // 0..63
  const int sk = ((t & 7) ^ (sr & 7)) * 8;

  auto STAGE = [&](int kb, int buf){
    unsigned short* Al = lds + buf*16384;
    unsigned short* Bl = Al + 8192;
    #pragma unroll
    for (int i=0;i<2;i++){
      int r = i*64 + sr;
      glds16(&Al[i*4096 + w*512], &Ab[(size_t)r*RS + ((kb + sk) & KM)]);
      glds16(&Bl[i*4096 + w*512], &Wb[(size_t)r*KP + kb + sk]);
    }
  };

  STAGE(0, 0);
  int cur = 0;
  #pragma unroll
  for (int kb = 0; kb < KP; kb += 64){
    if (kb + 64 < KP){
      STAGE(kb + 64, cur^1);
      VMCNT4;
    } else {
      VMCNT0;
    }
    SBAR; SCHEDB;
    const unsigned short* Al = lds + cur*16384;
    const unsigned short* Bl = Al + 8192;
    #pragma unroll
    for (int ks2=0; ks2<2; ks2++){
      bf16x8 a[4], bf[2];
      #pragma unroll
      for (int mi=0;mi<4;mi++){
        int r = wr + mi*16 + col;
        int j = (ks2*4 + q) ^ (r & 7);
        a[mi] = *(const bf16x8*)&Al[r*64 + j*8];
      }
      #pragma unroll
      for (int ni=0;ni<2;ni++){
        int r = wc + ni*16 + col;
        int j = (ks2*4 + q) ^ (r & 7);
        bf[ni] = *(const bf16x8*)&Bl[r*64 + j*8];
      }
      #pragma unroll
      for (int mi=0;mi<4;mi++)
        #pragma unroll
        for (int ni=0;ni<2;ni++)
          acc[mi][ni] = __builtin_amdgcn_mfma_f32_16x16x32_bf16(a[mi], bf[ni], acc[mi][ni], 0,0,0);
    }
    SCHEDB; LGKM0; SBAR;
    cur ^= 1;
  }
}

// ====== fused dual-GEMM 64x128 8-wave pipelined core (gruB) ======
// 512 threads. Wave w: all 64 rows, cols w*16 -> acc[4] per GEMM.
// 16 steps: s=0..7 -> ai (A1@W1), s=8..15 -> ah (A2@W2). 3 glds16/thread/step.
__device__ __forceinline__ void mm64x2_core(
    const unsigned short* __restrict__ A1, const unsigned short* __restrict__ W1,
    const unsigned short* __restrict__ A2, const unsigned short* __restrict__ W2,
    unsigned short* lds, floatx4 (&ai)[4], floatx4 (&ah)[4])
{
  const int t = threadIdx.x;
  const int w = t >> 6, lane = t & 63;
  const int q = lane >> 4, col = lane & 15;
  const int wc = w*16;
  const int sr = t >> 3;                 // 0..63
  const int sk = ((t & 7) ^ (sr & 7)) * 8;

  auto STAGE = [&](int s, int buf){
    const unsigned short* A = (s < 8) ? A1 : A2;
    const unsigned short* W = (s < 8) ? W1 : W2;
    int kb = (s & 7) * 64;
    unsigned short* Al = lds + buf*12288;
    unsigned short* Bl = Al + 4096;
    glds16(&Al[w*512], &A[(size_t)sr*512 + ((kb + sk) & 255)]);
    #pragma unroll
    for (int i=0;i<2;i++){
      int r = i*64 + sr;
      glds16(&Bl[i*4096 + w*512], &W[(size_t)r*512 + kb + sk]);
    }
  };

  STAGE(0, 0);
  int cur = 0;
  #pragma unroll
  for (int s = 0; s < 16; s++){
    if (s < 15){
      STAGE(s + 1, cur^1);
      VMCNT3;
    } else {
      VMCNT0;
    }
    SBAR; SCHEDB;
    const unsigned short* Al = lds + cur*12288;
    const unsigned short* Bl = Al + 4096;
    #pragma unroll
    for (int ks2=0; ks2<2; ks2++){
      bf16x8 a[4], bf;
      #pragma unroll
      for (int mi=0;mi<4;mi++){
        int r = mi*16 + col;
        int j = (ks2*4 + q) ^ (r & 7);
        a[mi] = *(const bf16x8*)&Al[r*64 + j*8];
      }
      {
        int r = wc + col;
        int j = (ks2*4 + q) ^ (r & 7);
        bf = *(const bf16x8*)&Bl[r*64 + j*8];
      }
      if (s < 8){
        #pragma unroll
        for (int mi=0;mi<4;mi++)
          ai[mi] = __builtin_amdgcn_mfma_f32_16x16x32_bf16(a[mi], bf, ai[mi], 0,0,0);
      } else {
        #pragma unroll
        for (int mi=0;mi<4;mi++)
          ah[mi] = __builtin_amdgcn_mfma_f32_16x16x32_bf16(a[mi], bf, ah[mi], 0,0,0);
      }
    }
    SCHEDB; LGKM0; SBAR;
    cur ^= 1;
  }
}

// XCD-aligned 1-D grid decode: row-block rb lands on XCD rb%8.
#define XDECODE(NCOL) \
  const int bid_ = blockIdx.x; \
  const int rb_ = ((bid_ >> 3) / NCOL) * 8 + (bid_ & 7); \
  const int colb_ = (bid_ >> 3) % NCOL; \
  if (rb_ >= RBLK) return;

#define XDECODE128(NCOL) \
  const int bid_ = blockIdx.x; \
  const int rb_ = ((bid_ >> 3) / NCOL) * 8 + (bid_ & 7); \
  const int colb_ = (bid_ >> 3) % NCOL; \
  if (rb_ >= RBLK128) return;

#define MMPRO128 \
  const int t = threadIdx.x, w = t >> 6, lane = t & 63; \
  const int q = lane >> 4, col = lane & 15; \
  const int wrq = (w >> 2) * 64, wcq = (w & 3) * 32; \
  floatx4 acc[4][2]; \
  _Pragma("unroll") for (int mi=0;mi<4;mi++) _Pragma("unroll") for (int ni=0;ni<2;ni++) \
    acc[mi][ni] = (floatx4){0.f,0.f,0.f,0.f};

// ---- Z = leaky(h @ W1cat^T + b1): NCOL=4; h read from ihcat h-half ----
__global__ __launch_bounds__(512,4) void z64_kernel(
    const unsigned short* __restrict__ ihcat, const unsigned short* __restrict__ w1cat,
    const float* __restrict__ eb1, unsigned short* __restrict__ Z)
{
  __shared__ unsigned short lds[32768];
  XDECODE128(4)
  const int row0 = rb_*128, col0 = colb_*128;
  MMPRO128
  mm128_core<256,512,255>(ihcat + (size_t)row0*512 + 256, w1cat + (size_t)col0*256, lds, acc);

  #pragma unroll
  for (int ni=0;ni<2;ni++){
    int n = col0 + wcq + ni*16 + col;
    int si = n >> 8, cz = n & 255;
    float bb = eb1[si*256 + cz];
    unsigned short* zp = Z + (size_t)si*MROWS*256 + cz;
    #pragma unroll
    for (int mi=0;mi<4;mi++)
      #pragma unroll
      for (int rr=0;rr<4;rr++){
        int row = row0 + wrq + mi*16 + q*4 + rr;
        zp[(size_t)row*256] = f2bf_u(leakyf(acc[mi][ni][rr] + bb));
      }
  }
}

// ---- CSR aggregate, XCD-pinned to stream: g = bid & 7 ----
// Paired-row gather: lanes 0-31 process node d, lanes 32-63 node d+1.
// Unroll-8: sums as two sequential 4-groups (FP order == 4-unrolled loop).
__global__ __launch_bounds__(256) void aggregate_kernel(
    const unsigned short* __restrict__ Z, const int* __restrict__ ssrc,
    const int* __restrict__ off, unsigned short* __restrict__ Sb)
{
  const int bid = blockIdx.x;          // 5000
  const int g = bid & 7;
  const int dgrp = bid >> 3;           // 0..624
  const int b = g >> 1, si = g & 1;
  const int w = threadIdx.x >> 6, lane = threadIdx.x & 63;
  const int half = lane >> 5, c = lane & 31;
  const unsigned short* zb = Z + ((size_t)si*MROWS + b*10000)*256 + c*8;
  const int* sp = ssrc + (size_t)g*NEDGES;
  const int* offg = off + g*(NNODES+1);

  #pragma unroll
  for (int p=0;p<2;p++){
    const int d = dgrp*16 + w*4 + p*2 + half;
    int j = offg[d];
    const int j1 = offg[d+1];
    float a0=0.f,a1=0.f,a2=0.f,a3=0.f,a4=0.f,a5=0.f,a6=0.f,a7=0.f;
    for (; j+8 <= j1; j+=8){
      int s[8];
      #pragma unroll
      for (int e=0;e<8;e++) s[e] = sp[j+e];
      ushort8v u[8];
      #pragma unroll
      for (int e=0;e<8;e++) u[e] = *(const ushort8v*)&zb[(size_t)s[e]*256];
      a0 += bfdec(u[0][0])+bfdec(u[1][0])+bfdec(u[2][0])+bfdec(u[3][0]);
      a1 += bfdec(u[0][1])+bfdec(u[1][1])+bfdec(u[2][1])+bfdec(u[3][1]);
      a2 += bfdec(u[0][2])+bfdec(u[1][2])+bfdec(u[2][2])+bfdec(u[3][2]);
      a3 += bfdec(u[0][3])+bfdec(u[1][3])+bfdec(u[2][3])+bfdec(u[3][3]);
      a4 += bfdec(u[0][4])+bfdec(u[1][4])+bfdec(u[2][4])+bfdec(u[3][4]);
      a5 += bfdec(u[0][5])+bfdec(u[1][5])+bfdec(u[2][5])+bfdec(u[3][5]);
      a6 += bfdec(u[0][6])+bfdec(u[1][6])+bfdec(u[2][6])+bfdec(u[3][6]);
      a7 += bfdec(u[0][7])+bfdec(u[1][7])+bfdec(u[2][7])+bfdec(u[3][7]);
      a0 += bfdec(u[4][0])+bfdec(u[5][0])+bfdec(u[6][0])+bfdec(u[7][0]);
      a1 += bfdec(u[4][1])+bfdec(u[5][1])+bfdec(u[6][1])+bfdec(u[7][1]);
      a2 += bfdec(u[4][2])+bfdec(u[5][2])+bfdec(u[6][2])+bfdec(u[7][2]);
      a3 += bfdec(u[4][3])+bfdec(u[5][3])+bfdec(u[6][3])+bfdec(u[7][3]);
      a4 += bfdec(u[4][4])+bfdec(u[5][4])+bfdec(u[6][4])+bfdec(u[7][4]);
      a5 += bfdec(u[4][5])+bfdec(u[5][5])+bfdec(u[6][5])+bfdec(u[7][5]);
      a6 += bfdec(u[4][6])+bfdec(u[5][6])+bfdec(u[6][6])+bfdec(u[7][6]);
      a7 += bfdec(u[4][7])+bfdec(u[5][7])+bfdec(u[6][7])+bfdec(u[7][7]);
    }
    for (; j+4 <= j1; j+=4){
      int s0=sp[j], s1=sp[j+1], s2=sp[j+2], s3=sp[j+3];
      ushort8v u0 = *(const ushort8v*)&zb[(size_t)s0*256];
      ushort8v u1 = *(const ushort8v*)&zb[(size_t)s1*256];
      ushort8v u2 = *(const ushort8v*)&zb[(size_t)s2*256];
      ushort8v u3 = *(const ushort8v*)&zb[(size_t)s3*256];
      a0 += bfdec(u0[0])+bfdec(u1[0])+bfdec(u2[0])+bfdec(u3[0]);
      a1 += bfdec(u0[1])+bfdec(u1[1])+bfdec(u2[1])+bfdec(u3[1]);
      a2 += bfdec(u0[2])+bfdec(u1[2])+bfdec(u2[2])+bfdec(u3[2]);
      a3 += bfdec(u0[3])+bfdec(u1[3])+bfdec(u2[3])+bfdec(u3[3]);
      a4 += bfdec(u0[4])+bfdec(u1[4])+bfdec(u2[4])+bfdec(u3[4]);
      a5 += bfdec(u0[5])+bfdec(u1[5])+bfdec(u2[5])+bfdec(u3[5]);
      a6 += bfdec(u0[6])+bfdec(u1[6])+bfdec(u2[6])+bfdec(u3[6]);
      a7 += bfdec(u0[7])+bfdec(u1[7])+bfdec(u2[7])+bfdec(u3[7]);
    }
    for (; j < j1; j++){
      ushort8v u = *(const ushort8v*)&zb[(size_t)sp[j]*256];
      a0+=bfdec(u[0]); a1+=bfdec(u[1]); a2+=bfdec(u[2]); a3+=bfdec(u[3]);
      a4+=bfdec(u[4]); a5+=bfdec(u[5]); a6+=bfdec(u[6]); a7+=bfdec(u[7]);
    }
    size_t so = (size_t)(b*10000 + d)*512 + si*256 + c*8;
    ushort8v hv;
    hv[0]=f2bf_u(a0); hv[1]=f2bf_u(a1); hv[2]=f2bf_u(a2); hv[3]=f2bf_u(a3);
    hv[4]=f2bf_u(a4); hv[5]=f2bf_u(a5); hv[6]=f2bf_u(a6); hv[7]=f2bf_u(a7);
    *(ushort8v*)&Sb[so] = hv;
  }
}

// ---- ihcat.ib = S @ W2k^T (2-term K'=1024) + deg.b2: NCOL=2 ----
__global__ __launch_bounds__(512,4) void w264_kernel(
    const unsigned short* __restrict__ Sb, const unsigned short* __restrict__ w2k,
    const float* __restrict__ eb2, const int* __restrict__ off,
    unsigned short* __restrict__ ihcat)
{
  __shared__ unsigned short lds[32768];
  XDECODE128(2)
  const int row0 = rb_*128, col0 = colb_*128;
  MMPRO128
  mm128_core<1024,512,511>(Sb + (size_t)row0*512, w2k + (size_t)col0*1024, lds, acc);

  float b20[2], b21[2];
  #pragma unroll
  for (int ni=0;ni<2;ni++){
    int n = col0 + wcq + ni*16 + col;
    b20[ni] = eb2[n];
    b21[ni] = eb2[256 + n];
  }
  #pragma unroll
  for (int mi=0;mi<4;mi++)
    #pragma unroll
    for (int rr=0;rr<4;rr++){
      int row = row0 + wrq + mi*16 + q*4 + rr;
      int rw = (row < 40000) ? row : 39999;   // guard padding rows (off lookup only)
      int b = rw / 10000, d = rw - b*10000;
      int o0 = (b*2)*(NNODES+1) + d;
      int o1 = (b*2+1)*(NNODES+1) + d;
      float dg0 = (float)(off[o0+1] - off[o0]);
      float dg1 = (float)(off[o1+1] - off[o1]);
      #pragma unroll
      for (int ni=0;ni<2;ni++){
        int n = col0 + wcq + ni*16 + col;
        ihcat[(size_t)row*512 + n] = f2bf_u(acc[mi][ni][rr] + dg0*b20[ni] + dg1*b21[ni]);
      }
    }
}

// ---- gruA: combined r,z GEMM -> u16 gates. NCOL=4 ----
__global__ __launch_bounds__(512,4) void gruA_kernel(
    const unsigned short* __restrict__ ihcat, const unsigned short* __restrict__ wcomb,
    const float* __restrict__ b_ih, const float* __restrict__ b_hh,
    unsigned short* __restrict__ rz_r, unsigned short* __restrict__ rz_z)
{
  __shared__ unsigned short lds[32768];
  XDECODE128(4)
  const int row0 = rb_*128, col0 = colb_*128;
  MMPRO128
  mm128_core<1024,512,511>(ihcat + (size_t)row0*512, wcomb + (size_t)col0*1024, lds, acc);

  float bb[2];
  #pragma unroll
  for (int ni=0;ni<2;ni++){
    int n = col0 + wcq + ni*16 + col;
    bb[ni] = b_ih[n] + b_hh[n];
  }
  unsigned short* dst = (col0 < 256) ? rz_r : rz_z;
  const int cbase = (col0 & 255) + wcq;
  #pragma unroll
  for (int mi=0;mi<4;mi++)
    #pragma unroll
    for (int rr=0;rr<4;rr++){
      size_t row = (size_t)(row0 + wrq + mi*16 + q*4 + rr);
      #pragma unroll
      for (int ni=0;ni<2;ni++){
        float v = fsig(acc[mi][ni][rr] + bb[ni]);
        dst[row*256 + cbase + ni*16 + col] = (unsigned short)(v*GATE_SCL + 0.5f);
      }
    }
}

// ---- gruB: n gate + GRU update. NCOL=2. Writes ihcat_nxt h-half + h_lo ----
__global__ __launch_bounds__(512,4) void gruB_kernel(
    const unsigned short* __restrict__ ihcat, unsigned short* __restrict__ h_lo,
    const unsigned short* __restrict__ wihk, const unsigned short* __restrict__ whhk,
    const float* __restrict__ b_ih, const float* __restrict__ b_hh,
    const unsigned short* __restrict__ rz_r, const unsigned short* __restrict__ rz_z,
    unsigned short* __restrict__ ihcat_nxt)
{
  __shared__ unsigned short lds[24576];
  XDECODE(2)
  const int row0 = rb_*64, dcol0 = colb_*128;   // n-gate W cols = 512 + dcol0
  const int t = threadIdx.x, w = t >> 6, lane = t & 63;
  const int q = lane >> 4, col = lane & 15;

  floatx4 ai[4], ah[4];
  #pragma unroll
  for (int mi=0;mi<4;mi++){ ai[mi] = (floatx4){0.f,0.f,0.f,0.f}; ah[mi] = (floatx4){0.f,0.f,0.f,0.f}; }

  mm64x2_core(ihcat + (size_t)row0*512,       wihk + (size_t)(512 + dcol0)*512,
              ihcat + (size_t)row0*512 + 256, whhk + (size_t)(512 + dcol0)*512,
              lds, ai, ah);

  const int dn = dcol0 + w*16 + col;
  const float bi = b_ih[512 + dn];
  const float bh = b_hh[512 + dn];
  #pragma unroll
  for (int mi=0;mi<4;mi++)
    #pragma unroll
    for (int rr=0;rr<4;rr++){
      size_t row = (size_t)(row0 + mi*16 + q*4 + rr);
      float rg = (float)rz_r[row*256 + dn] * GATE_INV;
      float zg = (float)rz_z[row*256 + dn] * GATE_INV;
      float ng = ftanh(ai[mi][rr] + bi + rg*(ah[mi][rr] + bh));
      float hv = bfdec(ihcat[row*512 + 256 + dn]) + bfdec(h_lo[row*256 + dn]);
      float hnew = (1.f - zg)*ng + zg*hv;
      unsigned short hh = f2bf_u(hnew);
      ihcat_nxt[row*512 + 256 + dn] = hh;
      h_lo[row*256 + dn] = f2bf_u(hnew - bfdec(hh));
    }
}

__global__ void reduce_kernel(const unsigned short* __restrict__ ihcat,
                              const unsigned short* __restrict__ h_lo,
                              float* __restrict__ sbuf){
  int b  = blockIdx.x / 50;
  int s0 = (blockIdx.x % 50) * 200;
  int d  = threadIdx.x;
  size_t row = (size_t)b*NNODES + s0;
  float acc = 0.f;
  for (int i=0;i<200;i++){
    acc += bfdec(ihcat[(row+i)*512 + 256 + d]) + bfdec(h_lo[(row+i)*256 + d]);
  }
  atomicAdd(&sbuf[b*DIM + d], acc);
}

__global__ __launch_bounds__(320) void head_kernel(
    const float* __restrict__ sbuf, const float* __restrict__ pt,
    const float* __restrict__ fc1w, const float* __restrict__ fc1b,
    const float* __restrict__ fc2w, const float* __restrict__ fc2b,
    const float* __restrict__ fc3w, const float* __restrict__ fc3b,
    float* __restrict__ out)
{
  __shared__ float L[4][257];
  __shared__ float T1[4][80];
  __shared__ float T2[4][80];
  __shared__ float fmx[4];
  int t = threadIdx.x;
  if (t < 256){
    for (int b=0;b<4;b++){
      float v = sbuf[b*DIM + t];
      float ll = logf(v);
      if (ll != ll) ll = 0.f;
      ll = fmaxf(ll, 0.f);
      L[b][t] = ll;
    }
  }
  __syncthreads();
  int w = t >> 6, lane = t & 63;
  if (w < 4){
    float m = -INFINITY;
    for (int i=lane;i<256;i+=64){ float v = L[w][i]; if (v != INFINITY) m = fmaxf(m, v); }
    #pragma unroll
    for (int o=32;o>=1;o>>=1) m = fmaxf(m, __shfl_xor(m, o, 64));
    if (lane==0) fmx[w] = m;
  }
  __syncthreads();
  if (t < 256){
    for (int b=0;b<4;b++) if (L[b][t] == INFINITY) L[b][t] = fmx[b];
  }
  if (t < 4) L[t][256] = pt[t];
  __syncthreads();
  if (t < 320){
    int b = t/80, i = t%80;
    float a = fc1b[i];
    for (int k=0;k<257;k++) a += L[b][k]*fc1w[i*257+k];
    T1[b][i] = leakyf(a);
  }
  __syncthreads();
  if (t < 320){
    int b = t/80, i = t%80;
    float a = fc2b[i];
    for (int k=0;k<80;k++) a += T1[b][k]*fc2w[i*80+k];
    T2[b][i] = leakyf(a);
  }
  __syncthreads();
  if (t < 40){
    int b = t/10, i = t%10;
    float a = fc3b[i];
    for (int k=0;k<80;k++) a += T2[b][k]*fc3w[i*80+k];
    out[b*10+i] = a;
  }
}

extern "C" void kernel_launch(void* const* d_in, const int* in_sizes, int n_in,
                              void* d_out, int out_size, void* d_ws, size_t ws_size,
                              hipStream_t stream) {
  const float* nodes = (const float*)d_in[0];
  const int*   edges = (const int*)d_in[1];
  const float* pt    = (const float*)d_in[2];
  const float* w_ih  = (const float*)d_in[3];
  const float* w_hh  = (const float*)d_in[4];
  const float* b_ih  = (const float*)d_in[5];
  const float* b_hh  = (const float*)d_in[6];
  const float* ew1   = (const float*)d_in[7];
  const float* eb1   = (const float*)d_in[8];
  const float* ew2   = (const float*)d_in[9];
  const float* eb2   = (const float*)d_in[10];
  const float* fc1w  = (const float*)d_in[11];
  const float* fc1b  = (const float*)d_in[12];
  const float* fc2w  = (const float*)d_in[13];
  const float* fc2b  = (const float*)d_in[14];
  const float* fc3w  = (const float*)d_in[15];
  const float* fc3b  = (const float*)d_in[16];

  const size_t HN  = (size_t)BATCH*NNODES*DIM;    // 10,240,000 (real rows)
  const size_t HNP = (size_t)MROWS*DIM;
  char* p = (char*)d_ws;
  float* sbuf = (float*)p;                        p += BATCH*DIM*4;
  unsigned short* ihcat0 = (unsigned short*)p;    p += (size_t)MROWS*512*2;  // [ib | h]
  unsigned short* ihcat1 = (unsigned short*)p;    p += (size_t)MROWS*512*2;
  unsigned short* h_lo   = (unsigned short*)p;    p += HNP*2;
  unsigned short* Zb   = (unsigned short*)p;      p += 2*HNP*2;              // z/agg scratch
  unsigned short* Sb   = (unsigned short*)p;      p += (size_t)MROWS*512*2;  // dead after w2 -> rz
  unsigned short* w1cat= (unsigned short*)p;      p += 512*256*2;
  unsigned short* w2k  = (unsigned short*)p;      p += 256*1024*2;
  unsigned short* wihk = (unsigned short*)p;      p += 768*512*2;
  unsigned short* whhk = (unsigned short*)p;      p += 768*512*2;
  unsigned short* wcomb= (unsigned short*)p;      p += 512*1024*2;
  int* off  = (int*)p;                            p += NG*(NNODES+1)*4;
  int* cur  = (int*)p;                            p += NG*NNODES*4;
  int* ssrc = (int*)p;                            p += (size_t)NG*NEDGES*4;

  unsigned short* rz_r = (unsigned short*)Sb;              // MROWS*256 u16
  unsigned short* rz_z = rz_r + (size_t)MROWS*256;         // MROWS*256 u16

  // weights
  w1cat_kernel<<<512,256,0,stream>>>(ew1, w1cat);
  w2k_kernel<<<1024,256,0,stream>>>(ew2, w2k);
  wk2_kernel<<<1536,256,0,stream>>>(w_ih, wihk);
  wk2_kernel<<<1536,256,0,stream>>>(w_hh, whhk);
  wcomb_kernel<<<2048,256,0,stream>>>(w_ih, w_hh, wcomb);

  // h0
  ihinit_kernel<<<(int)(HN/256),256,0,stream>>>(nodes, ihcat0, h_lo);

  // counting sort (CSR) of edges by dst, per stream g
  hipMemsetAsync(cur, 0, NG*NNODES*sizeof(int), stream);
  hist_kernel<<<(NG*NEDGES)/256,256,0,stream>>>(edges, cur);
  scan_kernel<<<NG,256,0,stream>>>(cur, off);
  hipMemsetAsync(cur, 0, NG*NNODES*sizeof(int), stream);
  scatter_kernel<<<(NG*NEDGES)/256,256,0,stream>>>(edges, off, cur, ssrc);

  hipMemsetAsync(sbuf, 0, BATCH*DIM*sizeof(float), stream);

  unsigned short* ih[2] = {ihcat0, ihcat1};

  for (int pass=0; pass<6; pass++){
    unsigned short* curb = ih[pass & 1];
    unsigned short* nxtb = ih[(pass+1) & 1];
    z64_kernel<<<RGRP128*8*4,512,0,stream>>>(curb, w1cat, eb1, Zb);
    aggregate_kernel<<<5000,256,0,stream>>>(Zb, ssrc, off, Sb);
    w264_kernel<<<RGRP128*8*2,512,0,stream>>>(Sb, w2k, eb2, off, curb);
    gruA_kernel<<<RGRP128*8*4,512,0,stream>>>(curb, wcomb, b_ih, b_hh, rz_r, rz_z);
    gruB_kernel<<<RGRP*8*2,512,0,stream>>>(curb, h_lo, wihk, whhk, b_ih, b_hh,
                                           rz_r, rz_z, nxtb);
  }
  reduce_kernel<<<200,256,0,stream>>>(ih[0], h_lo, sbuf);
  head_kernel<<<1,320,0,stream>>>(sbuf, pt, fc1w,fc1b,fc2w,fc2b,fc3w,fc3b,(float*)d_out);
}

// Round 5
// 1509.667 us; speedup vs baseline: 1.1415x; 1.0380x over previous
//
#include <hip/hip_runtime.h>
#include <math.h>

#define NNODES 10000
#define NEDGES 160000
#define DIM    256
#define BATCH  4
#define NG     8           // BATCH * S streams
#define MROWS  40064       // buffer row stride (40000 real rows)
#define RBLK   625         // 64-row blocks (gruB)
#define RGRP   79          // ceil(625/8)
#define RBLK128 313        // 128-row blocks (z64/w264/gruA): 313*128 = 40064
#define RGRP128 40         // ceil(313/8)

typedef __attribute__((ext_vector_type(8))) __bf16 bf16x8;
typedef __attribute__((ext_vector_type(4))) float  floatx4;
typedef __attribute__((ext_vector_type(8))) unsigned short ushort8v;

__device__ __forceinline__ float leakyf(float x){ return x > 0.f ? x : 0.01f*x; }
__device__ __forceinline__ float fsig(float x){ return 1.f/(1.f + __expf(-x)); }
__device__ __forceinline__ float ftanh(float x){ return 1.f - 2.f/(1.f + __expf(2.f*x)); }
__device__ __forceinline__ unsigned short f2bf_u(float x){
  unsigned int u = __float_as_uint(x);
  u += 0x7fffu + ((u >> 16) & 1u);
  return (unsigned short)(u >> 16);
}
__device__ __forceinline__ float bfdec(unsigned short u){
  return __uint_as_float(((unsigned int)u) << 16);
}
#define GATE_SCL 65535.f
#define GATE_INV 1.5259021896696422e-5f

#define VMCNT4 asm volatile("s_waitcnt vmcnt(4)" ::: "memory")
#define VMCNT3 asm volatile("s_waitcnt vmcnt(3)" ::: "memory")
#define VMCNT0 asm volatile("s_waitcnt vmcnt(0)" ::: "memory")
#define LGKM0  asm volatile("s_waitcnt lgkmcnt(0)" ::: "memory")
#define SBAR   __builtin_amdgcn_s_barrier()
#define SCHEDB __builtin_amdgcn_sched_barrier(0)

__device__ __forceinline__ void glds16(unsigned short* lds, const unsigned short* g){
  __builtin_amdgcn_global_load_lds(
      (const __attribute__((address_space(1))) void*)g,
      (__attribute__((address_space(3))) void*)lds, 16, 0, 0);
}

// h0: nodes -> ihcat0 h-half (hi) + h_lo. float4 in, ushort4 out.
__global__ void ihinit_kernel(const float* __restrict__ nodes,
                              unsigned short* __restrict__ ihcat,
                              unsigned short* __restrict__ h_lo){
  int idx = blockIdx.x*256 + threadIdx.x;   // 2,560,000
  int base = idx*4;
  int row = base >> 8, d = base & 255;
  float4 v = *(const float4*)&nodes[base];
  unsigned short h0=f2bf_u(v.x), h1=f2bf_u(v.y), h2=f2bf_u(v.z), h3=f2bf_u(v.w);
  ushort4 hi; hi.x=h0; hi.y=h1; hi.z=h2; hi.w=h3;
  *(ushort4*)&ihcat[(size_t)row*512 + 256 + d] = hi;
  ushort4 lo;
  lo.x = f2bf_u(v.x - bfdec(h0));
  lo.y = f2bf_u(v.y - bfdec(h1));
  lo.z = f2bf_u(v.z - bfdec(h2));
  lo.w = f2bf_u(v.w - bfdec(h3));
  *(ushort4*)&h_lo[base] = lo;
}

// ---- weight prep ----
__global__ void w1cat_kernel(const float* __restrict__ ew1, unsigned short* __restrict__ o){
  int idx = blockIdx.x*256 + threadIdx.x;      // 512*256
  int n = idx >> 8, k = idx & 255;
  o[idx] = f2bf_u(ew1[(n>>8)*65536 + (n&255)*256 + k]);
}
__global__ void w2k_kernel(const float* __restrict__ ew2, unsigned short* __restrict__ o){
  int idx = blockIdx.x*256 + threadIdx.x;      // 256*1024
  int n = idx >> 10, kp = idx & 1023;
  int j = kp & 511, term = kp >> 9;
  int si = j >> 8, k = j & 255;
  float v = ew2[si*65536 + n*256 + k];
  unsigned short h = f2bf_u(v);
  o[idx] = term ? f2bf_u(v - bfdec(h)) : h;
}
// wk2[c][kp], kp in [0,512): K' = [hi | lo]
__global__ void wk2_kernel(const float* __restrict__ w, unsigned short* __restrict__ o){
  int idx = blockIdx.x*256 + threadIdx.x;      // 768*512
  int c = idx >> 9, kp = idx & 511;
  int k = kp & 255, term = kp >> 8;
  float v = w[c*256 + k];
  unsigned short h = f2bf_u(v);
  o[idx] = term ? f2bf_u(v - bfdec(h)) : h;
}
// wcomb[c][kp], c in [0,512) (r,z rows), kp: [Wih_hi|Whh_hi|Wih_lo|Whh_lo]
__global__ void wcomb_kernel(const float* __restrict__ wih, const float* __restrict__ whh,
                             unsigned short* __restrict__ o){
  int idx = blockIdx.x*256 + threadIdx.x;      // 512*1024
  int c = idx >> 10, kp = idx & 1023;
  int seg = kp >> 8, k = kp & 255;
  const float* w = (seg & 1) ? whh : wih;
  float v = w[c*256 + k];
  unsigned short h = f2bf_u(v);
  o[idx] = (seg >> 1) ? f2bf_u(v - bfdec(h)) : h;
}

// ---------------- edge sort (counting sort by dst, per stream g) ----------------
// Stream g pinned to XCD g (g = bid & 7): all atomics/writes for stream g's
// cnt/ssrc regions issue from one XCD -> lines merge in its L2 (kills the
// 68 MB partial-line writeback amplification seen with block-range streams).
__global__ void hist_kernel(const int* __restrict__ edges, int* __restrict__ cnt){
  int bid = blockIdx.x;                  // 5000
  int g = bid & 7, chunk = bid >> 3;     // chunk 0..624
  int e = chunk*256 + threadIdx.x;
  int d = edges[((size_t)g*NEDGES + e)*2];
  atomicAdd(&cnt[g*NNODES + d], 1);
}

// parallel scan, phase A: per-chunk local exclusive scan + chunk totals
__global__ __launch_bounds__(256) void scanA_kernel(const int* __restrict__ cnt,
                                                    int* __restrict__ off,
                                                    int* __restrict__ tsum){
  __shared__ int sc[256];
  int bid = blockIdx.x;                  // 320
  int g = bid & 7, c = bid >> 3;         // c 0..39
  int t = threadIdx.x;
  int i = c*256 + t;
  int v = (i < NNODES) ? cnt[g*NNODES + i] : 0;
  sc[t] = v;
  __syncthreads();
  for (int o=1;o<256;o<<=1){
    int u = (t>=o) ? sc[t-o] : 0;
    __syncthreads();
    sc[t] += u;
    __syncthreads();
  }
  if (i < NNODES) off[g*(NNODES+1) + i] = sc[t] - v;
  if (t == 255) tsum[g*40 + c] = sc[255];
}
// phase C: add chunk-prefix base; write bucket-count total
__global__ __launch_bounds__(256) void scanC_kernel(const int* __restrict__ tsum,
                                                    int* __restrict__ off){
  __shared__ int ts[40];
  int bid = blockIdx.x;                  // 320
  int g = bid & 7, c = bid >> 3;
  int t = threadIdx.x;
  if (t < 40) ts[t] = tsum[g*40 + t];
  __syncthreads();
  int base = 0;
  for (int k=0;k<40;k++) base += (k < c) ? ts[k] : 0;
  int i = c*256 + t;
  if (i < NNODES) off[g*(NNODES+1) + i] += base;
  if (c == 39 && t == 0){
    int tot = 0;
    for (int k=0;k<40;k++) tot += ts[k];
    off[g*(NNODES+1) + NNODES] = tot;
  }
}

__global__ void scatter_kernel(const int* __restrict__ edges, const int* __restrict__ off,
                               int* __restrict__ cur, int* __restrict__ ssrc){
  int bid = blockIdx.x;                  // 5000
  int g = bid & 7, chunk = bid >> 3;
  int e = chunk*256 + threadIdx.x;
  const int* ep = &edges[((size_t)g*NEDGES + e)*2];
  int d = ep[0], s = ep[1];
  int pos = off[g*(NNODES+1) + d] + atomicAdd(&cur[g*NNODES + d], 1);
  ssrc[g*NEDGES + pos] = s;
}

// ====== 128x128 8-wave counted-vmcnt pipelined MFMA core ======
template<int KP, int RS, int KM>
__device__ __forceinline__ void mm128_core(
    const unsigned short* __restrict__ Ab, const unsigned short* __restrict__ Wb,
    unsigned short* lds, floatx4 (&acc)[4][2])
{
  const int t = threadIdx.x;
  const int w = t >> 6, lane = t & 63;
  const int q = lane >> 4, col = lane & 15;
  const int wr = (w >> 2) * 64;
  const int wc = (w & 3) * 32;
  const int sr = t >> 3;                 // 0..63
  const int sk = ((t & 7) ^ (sr & 7)) * 8;

  auto STAGE = [&](int kb, int buf){
    unsigned short* Al = lds + buf*16384;
    unsigned short* Bl = Al + 8192;
    #pragma unroll
    for (int i=0;i<2;i++){
      int r = i*64 + sr;
      glds16(&Al[i*4096 + w*512], &Ab[(size_t)r*RS + ((kb + sk) & KM)]);
      glds16(&Bl[i*4096 + w*512], &Wb[(size_t)r*KP + kb + sk]);
    }
  };

  STAGE(0, 0);
  int cur = 0;
  #pragma unroll
  for (int kb = 0; kb < KP; kb += 64){
    if (kb + 64 < KP){
      STAGE(kb + 64, cur^1);
      VMCNT4;
    } else {
      VMCNT0;
    }
    SBAR; SCHEDB;
    const unsigned short* Al = lds + cur*16384;
    const unsigned short* Bl = Al + 8192;
    #pragma unroll
    for (int ks2=0; ks2<2; ks2++){
      bf16x8 a[4], bf[2];
      #pragma unroll
      for (int mi=0;mi<4;mi++){
        int r = wr + mi*16 + col;
        int j = (ks2*4 + q) ^ (r & 7);
        a[mi] = *(const bf16x8*)&Al[r*64 + j*8];
      }
      #pragma unroll
      for (int ni=0;ni<2;ni++){
        int r = wc + ni*16 + col;
        int j = (ks2*4 + q) ^ (r & 7);
        bf[ni] = *(const bf16x8*)&Bl[r*64 + j*8];
      }
      #pragma unroll
      for (int mi=0;mi<4;mi++)
        #pragma unroll
        for (int ni=0;ni<2;ni++)
          acc[mi][ni] = __builtin_amdgcn_mfma_f32_16x16x32_bf16(a[mi], bf[ni], acc[mi][ni], 0,0,0);
    }
    SCHEDB; LGKM0; SBAR;
    cur ^= 1;
  }
}

// ====== fused dual-GEMM 64x128 8-wave pipelined core (gruB) ======
__device__ __forceinline__ void mm64x2_core(
    const unsigned short* __restrict__ A1, const unsigned short* __restrict__ W1,
    const unsigned short* __restrict__ A2, const unsigned short* __restrict__ W2,
    unsigned short* lds, floatx4 (&ai)[4], floatx4 (&ah)[4])
{
  const int t = threadIdx.x;
  const int w = t >> 6, lane = t & 63;
  const int q = lane >> 4, col = lane & 15;
  const int wc = w*16;
  const int sr = t >> 3;                 // 0..63
  const int sk = ((t & 7) ^ (sr & 7)) * 8;

  auto STAGE = [&](int s, int buf){
    const unsigned short* A = (s < 8) ? A1 : A2;
    const unsigned short* W = (s < 8) ? W1 : W2;
    int kb = (s & 7) * 64;
    unsigned short* Al = lds + buf*12288;
    unsigned short* Bl = Al + 4096;
    glds16(&Al[w*512], &A[(size_t)sr*512 + ((kb + sk) & 255)]);
    #pragma unroll
    for (int i=0;i<2;i++){
      int r = i*64 + sr;
      glds16(&Bl[i*4096 + w*512], &W[(size_t)r*512 + kb + sk]);
    }
  };

  STAGE(0, 0);
  int cur = 0;
  #pragma unroll
  for (int s = 0; s < 16; s++){
    if (s < 15){
      STAGE(s + 1, cur^1);
      VMCNT3;
    } else {
      VMCNT0;
    }
    SBAR; SCHEDB;
    const unsigned short* Al = lds + cur*12288;
    const unsigned short* Bl = Al + 4096;
    #pragma unroll
    for (int ks2=0; ks2<2; ks2++){
      bf16x8 a[4], bf;
      #pragma unroll
      for (int mi=0;mi<4;mi++){
        int r = mi*16 + col;
        int j = (ks2*4 + q) ^ (r & 7);
        a[mi] = *(const bf16x8*)&Al[r*64 + j*8];
      }
      {
        int r = wc + col;
        int j = (ks2*4 + q) ^ (r & 7);
        bf = *(const bf16x8*)&Bl[r*64 + j*8];
      }
      if (s < 8){
        #pragma unroll
        for (int mi=0;mi<4;mi++)
          ai[mi] = __builtin_amdgcn_mfma_f32_16x16x32_bf16(a[mi], bf, ai[mi], 0,0,0);
      } else {
        #pragma unroll
        for (int mi=0;mi<4;mi++)
          ah[mi] = __builtin_amdgcn_mfma_f32_16x16x32_bf16(a[mi], bf, ah[mi], 0,0,0);
      }
    }
    SCHEDB; LGKM0; SBAR;
    cur ^= 1;
  }
}

// XCD-aligned 1-D grid decode: row-block rb lands on XCD rb%8.
#define XDECODE(NCOL) \
  const int bid_ = blockIdx.x; \
  const int rb_ = ((bid_ >> 3) / NCOL) * 8 + (bid_ & 7); \
  const int colb_ = (bid_ >> 3) % NCOL; \
  if (rb_ >= RBLK) return;

#define XDECODE128(NCOL) \
  const int bid_ = blockIdx.x; \
  const int rb_ = ((bid_ >> 3) / NCOL) * 8 + (bid_ & 7); \
  const int colb_ = (bid_ >> 3) % NCOL; \
  if (rb_ >= RBLK128) return;

#define MMPRO128 \
  const int t = threadIdx.x, w = t >> 6, lane = t & 63; \
  const int q = lane >> 4, col = lane & 15; \
  const int wrq = (w >> 2) * 64, wcq = (w & 3) * 32; \
  floatx4 acc[4][2]; \
  _Pragma("unroll") for (int mi=0;mi<4;mi++) _Pragma("unroll") for (int ni=0;ni<2;ni++) \
    acc[mi][ni] = (floatx4){0.f,0.f,0.f,0.f};

// ---- Z = leaky(h @ W1cat^T + b1): NCOL=4; h read from ihcat h-half ----
__global__ __launch_bounds__(512,4) void z64_kernel(
    const unsigned short* __restrict__ ihcat, const unsigned short* __restrict__ w1cat,
    const float* __restrict__ eb1, unsigned short* __restrict__ Z)
{
  __shared__ unsigned short lds[32768];
  XDECODE128(4)
  const int row0 = rb_*128, col0 = colb_*128;
  MMPRO128
  mm128_core<256,512,255>(ihcat + (size_t)row0*512 + 256, w1cat + (size_t)col0*256, lds, acc);

  #pragma unroll
  for (int ni=0;ni<2;ni++){
    int n = col0 + wcq + ni*16 + col;
    int si = n >> 8, cz = n & 255;
    float bb = eb1[si*256 + cz];
    unsigned short* zp = Z + (size_t)si*MROWS*256 + cz;
    #pragma unroll
    for (int mi=0;mi<4;mi++)
      #pragma unroll
      for (int rr=0;rr<4;rr++){
        int row = row0 + wrq + mi*16 + q*4 + rr;
        zp[(size_t)row*256] = f2bf_u(leakyf(acc[mi][ni][rr] + bb));
      }
  }
}

// ---- CSR aggregate, XCD-pinned to stream: g = bid & 7 ----
// Paired-row gather, 16 rows in flight (mean degree = 16). Sums applied as
// sequential 4-groups -> FP order identical to the original 4-unrolled loop.
#define ACC4(B) do { \
  a0 += bfdec(u[B][0])+bfdec(u[B+1][0])+bfdec(u[B+2][0])+bfdec(u[B+3][0]); \
  a1 += bfdec(u[B][1])+bfdec(u[B+1][1])+bfdec(u[B+2][1])+bfdec(u[B+3][1]); \
  a2 += bfdec(u[B][2])+bfdec(u[B+1][2])+bfdec(u[B+2][2])+bfdec(u[B+3][2]); \
  a3 += bfdec(u[B][3])+bfdec(u[B+1][3])+bfdec(u[B+2][3])+bfdec(u[B+3][3]); \
  a4 += bfdec(u[B][4])+bfdec(u[B+1][4])+bfdec(u[B+2][4])+bfdec(u[B+3][4]); \
  a5 += bfdec(u[B][5])+bfdec(u[B+1][5])+bfdec(u[B+2][5])+bfdec(u[B+3][5]); \
  a6 += bfdec(u[B][6])+bfdec(u[B+1][6])+bfdec(u[B+2][6])+bfdec(u[B+3][6]); \
  a7 += bfdec(u[B][7])+bfdec(u[B+1][7])+bfdec(u[B+2][7])+bfdec(u[B+3][7]); \
} while(0)

__global__ __launch_bounds__(256) void aggregate_kernel(
    const unsigned short* __restrict__ Z, const int* __restrict__ ssrc,
    const int* __restrict__ off, unsigned short* __restrict__ Sb)
{
  const int bid = blockIdx.x;          // 5000
  const int g = bid & 7;
  const int dgrp = bid >> 3;           // 0..624
  const int b = g >> 1, si = g & 1;
  const int w = threadIdx.x >> 6, lane = threadIdx.x & 63;
  const int half = lane >> 5, c = lane & 31;
  const unsigned short* zb = Z + ((size_t)si*MROWS + b*10000)*256 + c*8;
  const int* sp = ssrc + (size_t)g*NEDGES;
  const int* offg = off + g*(NNODES+1);

  #pragma unroll
  for (int p=0;p<2;p++){
    const int d = dgrp*16 + w*4 + p*2 + half;
    int j = offg[d];
    const int j1 = offg[d+1];
    float a0=0.f,a1=0.f,a2=0.f,a3=0.f,a4=0.f,a5=0.f,a6=0.f,a7=0.f;
    for (; j+16 <= j1; j+=16){
      int s[16];
      #pragma unroll
      for (int e=0;e<16;e++) s[e] = sp[j+e];
      ushort8v u[16];
      #pragma unroll
      for (int e=0;e<16;e++) u[e] = *(const ushort8v*)&zb[(size_t)s[e]*256];
      ACC4(0); ACC4(4); ACC4(8); ACC4(12);
    }
    for (; j+4 <= j1; j+=4){
      int s[4];
      #pragma unroll
      for (int e=0;e<4;e++) s[e] = sp[j+e];
      ushort8v u[4];
      #pragma unroll
      for (int e=0;e<4;e++) u[e] = *(const ushort8v*)&zb[(size_t)s[e]*256];
      ACC4(0);
    }
    for (; j < j1; j++){
      ushort8v uu = *(const ushort8v*)&zb[(size_t)sp[j]*256];
      a0+=bfdec(uu[0]); a1+=bfdec(uu[1]); a2+=bfdec(uu[2]); a3+=bfdec(uu[3]);
      a4+=bfdec(uu[4]); a5+=bfdec(uu[5]); a6+=bfdec(uu[6]); a7+=bfdec(uu[7]);
    }
    size_t so = (size_t)(b*10000 + d)*512 + si*256 + c*8;
    ushort8v hv;
    hv[0]=f2bf_u(a0); hv[1]=f2bf_u(a1); hv[2]=f2bf_u(a2); hv[3]=f2bf_u(a3);
    hv[4]=f2bf_u(a4); hv[5]=f2bf_u(a5); hv[6]=f2bf_u(a6); hv[7]=f2bf_u(a7);
    *(ushort8v*)&Sb[so] = hv;
  }
}

// ---- ihcat.ib = S @ W2k^T (2-term K'=1024) + deg.b2: NCOL=2 ----
__global__ __launch_bounds__(512,4) void w264_kernel(
    const unsigned short* __restrict__ Sb, const unsigned short* __restrict__ w2k,
    const float* __restrict__ eb2, const int* __restrict__ off,
    unsigned short* __restrict__ ihcat)
{
  __shared__ unsigned short lds[32768];
  XDECODE128(2)
  const int row0 = rb_*128, col0 = colb_*128;
  MMPRO128
  mm128_core<1024,512,511>(Sb + (size_t)row0*512, w2k + (size_t)col0*1024, lds, acc);

  float b20[2], b21[2];
  #pragma unroll
  for (int ni=0;ni<2;ni++){
    int n = col0 + wcq + ni*16 + col;
    b20[ni] = eb2[n];
    b21[ni] = eb2[256 + n];
  }
  #pragma unroll
  for (int mi=0;mi<4;mi++)
    #pragma unroll
    for (int rr=0;rr<4;rr++){
      int row = row0 + wrq + mi*16 + q*4 + rr;
      int rw = (row < 40000) ? row : 39999;   // guard padding rows (off lookup only)
      int b = rw / 10000, d = rw - b*10000;
      int o0 = (b*2)*(NNODES+1) + d;
      int o1 = (b*2+1)*(NNODES+1) + d;
      float dg0 = (float)(off[o0+1] - off[o0]);
      float dg1 = (float)(off[o1+1] - off[o1]);
      #pragma unroll
      for (int ni=0;ni<2;ni++){
        int n = col0 + wcq + ni*16 + col;
        ihcat[(size_t)row*512 + n] = f2bf_u(acc[mi][ni][rr] + dg0*b20[ni] + dg1*b21[ni]);
      }
    }
}

// ---- gruA: combined r,z GEMM -> u16 gates. NCOL=4 ----
__global__ __launch_bounds__(512,4) void gruA_kernel(
    const unsigned short* __restrict__ ihcat, const unsigned short* __restrict__ wcomb,
    const float* __restrict__ b_ih, const float* __restrict__ b_hh,
    unsigned short* __restrict__ rz_r, unsigned short* __restrict__ rz_z)
{
  __shared__ unsigned short lds[32768];
  XDECODE128(4)
  const int row0 = rb_*128, col0 = colb_*128;
  MMPRO128
  mm128_core<1024,512,511>(ihcat + (size_t)row0*512, wcomb + (size_t)col0*1024, lds, acc);

  float bb[2];
  #pragma unroll
  for (int ni=0;ni<2;ni++){
    int n = col0 + wcq + ni*16 + col;
    bb[ni] = b_ih[n] + b_hh[n];
  }
  unsigned short* dst = (col0 < 256) ? rz_r : rz_z;
  const int cbase = (col0 & 255) + wcq;
  #pragma unroll
  for (int mi=0;mi<4;mi++)
    #pragma unroll
    for (int rr=0;rr<4;rr++){
      size_t row = (size_t)(row0 + wrq + mi*16 + q*4 + rr);
      #pragma unroll
      for (int ni=0;ni<2;ni++){
        float v = fsig(acc[mi][ni][rr] + bb[ni]);
        dst[row*256 + cbase + ni*16 + col] = (unsigned short)(v*GATE_SCL + 0.5f);
      }
    }
}

// ---- gruB: n gate + GRU update. NCOL=2. Writes ihcat_nxt h-half + h_lo ----
__global__ __launch_bounds__(512,4) void gruB_kernel(
    const unsigned short* __restrict__ ihcat, unsigned short* __restrict__ h_lo,
    const unsigned short* __restrict__ wihk, const unsigned short* __restrict__ whhk,
    const float* __restrict__ b_ih, const float* __restrict__ b_hh,
    const unsigned short* __restrict__ rz_r, const unsigned short* __restrict__ rz_z,
    unsigned short* __restrict__ ihcat_nxt)
{
  __shared__ unsigned short lds[24576];
  XDECODE(2)
  const int row0 = rb_*64, dcol0 = colb_*128;   // n-gate W cols = 512 + dcol0
  const int t = threadIdx.x, w = t >> 6, lane = t & 63;
  const int q = lane >> 4, col = lane & 15;

  floatx4 ai[4], ah[4];
  #pragma unroll
  for (int mi=0;mi<4;mi++){ ai[mi] = (floatx4){0.f,0.f,0.f,0.f}; ah[mi] = (floatx4){0.f,0.f,0.f,0.f}; }

  mm64x2_core(ihcat + (size_t)row0*512,       wihk + (size_t)(512 + dcol0)*512,
              ihcat + (size_t)row0*512 + 256, whhk + (size_t)(512 + dcol0)*512,
              lds, ai, ah);

  const int dn = dcol0 + w*16 + col;
  const float bi = b_ih[512 + dn];
  const float bh = b_hh[512 + dn];
  #pragma unroll
  for (int mi=0;mi<4;mi++)
    #pragma unroll
    for (int rr=0;rr<4;rr++){
      size_t row = (size_t)(row0 + mi*16 + q*4 + rr);
      float rg = (float)rz_r[row*256 + dn] * GATE_INV;
      float zg = (float)rz_z[row*256 + dn] * GATE_INV;
      float ng = ftanh(ai[mi][rr] + bi + rg*(ah[mi][rr] + bh));
      float hv = bfdec(ihcat[row*512 + 256 + dn]) + bfdec(h_lo[row*256 + dn]);
      float hnew = (1.f - zg)*ng + zg*hv;
      unsigned short hh = f2bf_u(hnew);
      ihcat_nxt[row*512 + 256 + dn] = hh;
      h_lo[row*256 + dn] = f2bf_u(hnew - bfdec(hh));
    }
}

__global__ void reduce_kernel(const unsigned short* __restrict__ ihcat,
                              const unsigned short* __restrict__ h_lo,
                              float* __restrict__ sbuf){
  int b  = blockIdx.x / 50;
  int s0 = (blockIdx.x % 50) * 200;
  int d  = threadIdx.x;
  size_t row = (size_t)b*NNODES + s0;
  float acc = 0.f;
  for (int i=0;i<200;i++){
    acc += bfdec(ihcat[(row+i)*512 + 256 + d]) + bfdec(h_lo[(row+i)*256 + d]);
  }
  atomicAdd(&sbuf[b*DIM + d], acc);
}

__global__ __launch_bounds__(320) void head_kernel(
    const float* __restrict__ sbuf, const float* __restrict__ pt,
    const float* __restrict__ fc1w, const float* __restrict__ fc1b,
    const float* __restrict__ fc2w, const float* __restrict__ fc2b,
    const float* __restrict__ fc3w, const float* __restrict__ fc3b,
    float* __restrict__ out)
{
  __shared__ float L[4][257];
  __shared__ float T1[4][80];
  __shared__ float T2[4][80];
  __shared__ float fmx[4];
  int t = threadIdx.x;
  if (t < 256){
    for (int b=0;b<4;b++){
      float v = sbuf[b*DIM + t];
      float ll = logf(v);
      if (ll != ll) ll = 0.f;
      ll = fmaxf(ll, 0.f);
      L[b][t] = ll;
    }
  }
  __syncthreads();
  int w = t >> 6, lane = t & 63;
  if (w < 4){
    float m = -INFINITY;
    for (int i=lane;i<256;i+=64){ float v = L[w][i]; if (v != INFINITY) m = fmaxf(m, v); }
    #pragma unroll
    for (int o=32;o>=1;o>>=1) m = fmaxf(m, __shfl_xor(m, o, 64));
    if (lane==0) fmx[w] = m;
  }
  __syncthreads();
  if (t < 256){
    for (int b=0;b<4;b++) if (L[b][t] == INFINITY) L[b][t] = fmx[b];
  }
  if (t < 4) L[t][256] = pt[t];
  __syncthreads();
  if (t < 320){
    int b = t/80, i = t%80;
    float a = fc1b[i];
    for (int k=0;k<257;k++) a += L[b][k]*fc1w[i*257+k];
    T1[b][i] = leakyf(a);
  }
  __syncthreads();
  if (t < 320){
    int b = t/80, i = t%80;
    float a = fc2b[i];
    for (int k=0;k<80;k++) a += T1[b][k]*fc2w[i*80+k];
    T2[b][i] = leakyf(a);
  }
  __syncthreads();
  if (t < 40){
    int b = t/10, i = t%10;
    float a = fc3b[i];
    for (int k=0;k<80;k++) a += T2[b][k]*fc3w[i*80+k];
    out[b*10+i] = a;
  }
}

extern "C" void kernel_launch(void* const* d_in, const int* in_sizes, int n_in,
                              void* d_out, int out_size, void* d_ws, size_t ws_size,
                              hipStream_t stream) {
  const float* nodes = (const float*)d_in[0];
  const int*   edges = (const int*)d_in[1];
  const float* pt    = (const float*)d_in[2];
  const float* w_ih  = (const float*)d_in[3];
  const float* w_hh  = (const float*)d_in[4];
  const float* b_ih  = (const float*)d_in[5];
  const float* b_hh  = (const float*)d_in[6];
  const float* ew1   = (const float*)d_in[7];
  const float* eb1   = (const float*)d_in[8];
  const float* ew2   = (const float*)d_in[9];
  const float* eb2   = (const float*)d_in[10];
  const float* fc1w  = (const float*)d_in[11];
  const float* fc1b  = (const float*)d_in[12];
  const float* fc2w  = (const float*)d_in[13];
  const float* fc2b  = (const float*)d_in[14];
  const float* fc3w  = (const float*)d_in[15];
  const float* fc3b  = (const float*)d_in[16];

  const size_t HN  = (size_t)BATCH*NNODES*DIM;    // 10,240,000 (real rows)
  const size_t HNP = (size_t)MROWS*DIM;
  char* p = (char*)d_ws;
  float* sbuf = (float*)p;                        p += BATCH*DIM*4;
  unsigned short* ihcat0 = (unsigned short*)p;    p += (size_t)MROWS*512*2;  // [ib | h]
  unsigned short* ihcat1 = (unsigned short*)p;    p += (size_t)MROWS*512*2;
  unsigned short* h_lo   = (unsigned short*)p;    p += HNP*2;
  unsigned short* Zb   = (unsigned short*)p;      p += 2*HNP*2;              // z/agg scratch
  unsigned short* Sb   = (unsigned short*)p;      p += (size_t)MROWS*512*2;  // dead after w2 -> rz
  unsigned short* w1cat= (unsigned short*)p;      p += 512*256*2;
  unsigned short* w2k  = (unsigned short*)p;      p += 256*1024*2;
  unsigned short* wihk = (unsigned short*)p;      p += 768*512*2;
  unsigned short* whhk = (unsigned short*)p;      p += 768*512*2;
  unsigned short* wcomb= (unsigned short*)p;      p += 512*1024*2;
  int* off  = (int*)p;                            p += NG*(NNODES+1)*4;
  int* cur  = (int*)p;                            p += NG*NNODES*4;
  int* ssrc = (int*)p;                            p += (size_t)NG*NEDGES*4;

  unsigned short* rz_r = (unsigned short*)Sb;              // MROWS*256 u16
  unsigned short* rz_z = rz_r + (size_t)MROWS*256;         // MROWS*256 u16
  int* tsum = (int*)sbuf;   // 8*40 ints; sbuf is memset AFTER scan/scatter

  // weights
  w1cat_kernel<<<512,256,0,stream>>>(ew1, w1cat);
  w2k_kernel<<<1024,256,0,stream>>>(ew2, w2k);
  wk2_kernel<<<1536,256,0,stream>>>(w_ih, wihk);
  wk2_kernel<<<1536,256,0,stream>>>(w_hh, whhk);
  wcomb_kernel<<<2048,256,0,stream>>>(w_ih, w_hh, wcomb);

  // h0
  ihinit_kernel<<<(int)(HN/1024),256,0,stream>>>(nodes, ihcat0, h_lo);

  // counting sort (CSR) of edges by dst, per stream g (stream pinned to XCD)
  hipMemsetAsync(cur, 0, NG*NNODES*sizeof(int), stream);
  hist_kernel<<<(NG*NEDGES)/256,256,0,stream>>>(edges, cur);
  scanA_kernel<<<NG*40,256,0,stream>>>(cur, off, tsum);
  scanC_kernel<<<NG*40,256,0,stream>>>(tsum, off);
  hipMemsetAsync(cur, 0, NG*NNODES*sizeof(int), stream);
  scatter_kernel<<<(NG*NEDGES)/256,256,0,stream>>>(edges, off, cur, ssrc);

  hipMemsetAsync(sbuf, 0, BATCH*DIM*sizeof(float), stream);

  unsigned short* ih[2] = {ihcat0, ihcat1};

  for (int pass=0; pass<6; pass++){
    unsigned short* curb = ih[pass & 1];
    unsigned short* nxtb = ih[(pass+1) & 1];
    z64_kernel<<<RGRP128*8*4,512,0,stream>>>(curb, w1cat, eb1, Zb);
    aggregate_kernel<<<5000,256,0,stream>>>(Zb, ssrc, off, Sb);
    w264_kernel<<<RGRP128*8*2,512,0,stream>>>(Sb, w2k, eb2, off, curb);
    gruA_kernel<<<RGRP128*8*4,512,0,stream>>>(curb, wcomb, b_ih, b_hh, rz_r, rz_z);
    gruB_kernel<<<RGRP*8*2,512,0,stream>>>(curb, h_lo, wihk, whhk, b_ih, b_hh,
                                           rz_r, rz_z, nxtb);
  }
  reduce_kernel<<<200,256,0,stream>>>(ih[0], h_lo, sbuf);
  head_kernel<<<1,320,0,stream>>>(sbuf, pt, fc1w,fc1b,fc2w,fc2b,fc3w,fc3b,(float*)d_out);
}

// Round 6
// 1428.231 us; speedup vs baseline: 1.2065x; 1.0570x over previous
//
#include <hip/hip_runtime.h>
#include <math.h>

#define NNODES 10000
#define NEDGES 160000
#define DIM    256
#define BATCH  4
#define NG     8           // BATCH * S streams
#define MROWS  40064       // buffer row stride (40000 real rows)
#define RBLK   625         // 64-row blocks (gruB)
#define RGRP   79          // ceil(625/8)
#define RBLK128 313        // 128-row blocks (z64/w264/gruA): 313*128 = 40064
#define RGRP128 40         // ceil(313/8)

typedef __attribute__((ext_vector_type(8))) __bf16 bf16x8;
typedef __attribute__((ext_vector_type(4))) float  floatx4;
typedef __attribute__((ext_vector_type(8))) unsigned short ushort8v;

__device__ __forceinline__ float leakyf(float x){ return x > 0.f ? x : 0.01f*x; }
__device__ __forceinline__ float fsig(float x){ return 1.f/(1.f + __expf(-x)); }
__device__ __forceinline__ float ftanh(float x){ return 1.f - 2.f/(1.f + __expf(2.f*x)); }
__device__ __forceinline__ unsigned short f2bf_u(float x){
  unsigned int u = __float_as_uint(x);
  u += 0x7fffu + ((u >> 16) & 1u);
  return (unsigned short)(u >> 16);
}
__device__ __forceinline__ float bfdec(unsigned short u){
  return __uint_as_float(((unsigned int)u) << 16);
}
#define GATE_SCL 65535.f
#define GATE_INV 1.5259021896696422e-5f

#define VMCNT4 asm volatile("s_waitcnt vmcnt(4)" ::: "memory")
#define VMCNT3 asm volatile("s_waitcnt vmcnt(3)" ::: "memory")
#define VMCNT0 asm volatile("s_waitcnt vmcnt(0)" ::: "memory")
#define LGKM0  asm volatile("s_waitcnt lgkmcnt(0)" ::: "memory")
#define SBAR   __builtin_amdgcn_s_barrier()
#define SCHEDB __builtin_amdgcn_sched_barrier(0)
#define PRIO1  __builtin_amdgcn_s_setprio(1)
#define PRIO0  __builtin_amdgcn_s_setprio(0)

__device__ __forceinline__ void glds16(unsigned short* lds, const unsigned short* g){
  __builtin_amdgcn_global_load_lds(
      (const __attribute__((address_space(1))) void*)g,
      (__attribute__((address_space(3))) void*)lds, 16, 0, 0);
}

// h0: nodes -> ihcat0 h-half (hi) + h_lo. float4 in, ushort4 out.
__global__ void ihinit_kernel(const float* __restrict__ nodes,
                              unsigned short* __restrict__ ihcat,
                              unsigned short* __restrict__ h_lo){
  int idx = blockIdx.x*256 + threadIdx.x;   // 2,560,000
  int base = idx*4;
  int row = base >> 8, d = base & 255;
  float4 v = *(const float4*)&nodes[base];
  unsigned short h0=f2bf_u(v.x), h1=f2bf_u(v.y), h2=f2bf_u(v.z), h3=f2bf_u(v.w);
  ushort4 hi; hi.x=h0; hi.y=h1; hi.z=h2; hi.w=h3;
  *(ushort4*)&ihcat[(size_t)row*512 + 256 + d] = hi;
  ushort4 lo;
  lo.x = f2bf_u(v.x - bfdec(h0));
  lo.y = f2bf_u(v.y - bfdec(h1));
  lo.z = f2bf_u(v.z - bfdec(h2));
  lo.w = f2bf_u(v.w - bfdec(h3));
  *(ushort4*)&h_lo[base] = lo;
}

// ---- weight prep ----
__global__ void w1cat_kernel(const float* __restrict__ ew1, unsigned short* __restrict__ o){
  int idx = blockIdx.x*256 + threadIdx.x;      // 512*256
  int n = idx >> 8, k = idx & 255;
  o[idx] = f2bf_u(ew1[(n>>8)*65536 + (n&255)*256 + k]);
}
__global__ void w2k_kernel(const float* __restrict__ ew2, unsigned short* __restrict__ o){
  int idx = blockIdx.x*256 + threadIdx.x;      // 256*1024
  int n = idx >> 10, kp = idx & 1023;
  int j = kp & 511, term = kp >> 9;
  int si = j >> 8, k = j & 255;
  float v = ew2[si*65536 + n*256 + k];
  unsigned short h = f2bf_u(v);
  o[idx] = term ? f2bf_u(v - bfdec(h)) : h;
}
// wk2[c][kp], kp in [0,512): K' = [hi | lo]
__global__ void wk2_kernel(const float* __restrict__ w, unsigned short* __restrict__ o){
  int idx = blockIdx.x*256 + threadIdx.x;      // 768*512
  int c = idx >> 9, kp = idx & 511;
  int k = kp & 255, term = kp >> 8;
  float v = w[c*256 + k];
  unsigned short h = f2bf_u(v);
  o[idx] = term ? f2bf_u(v - bfdec(h)) : h;
}
// wcomb[c][kp], c in [0,512) (r,z rows), kp: [Wih_hi|Whh_hi|Wih_lo|Whh_lo]
__global__ void wcomb_kernel(const float* __restrict__ wih, const float* __restrict__ whh,
                             unsigned short* __restrict__ o){
  int idx = blockIdx.x*256 + threadIdx.x;      // 512*1024
  int c = idx >> 10, kp = idx & 1023;
  int seg = kp >> 8, k = kp & 255;
  const float* w = (seg & 1) ? whh : wih;
  float v = w[c*256 + k];
  unsigned short h = f2bf_u(v);
  o[idx] = (seg >> 1) ? f2bf_u(v - bfdec(h)) : h;
}

// ---------------- edge sort (counting sort by dst, per stream g) ----------------
// Stream g pinned to XCD g (g = bid & 7): all atomics/writes for stream g's
// cnt/ssrc regions issue from one XCD -> lines merge in its L2.
__global__ void hist_kernel(const int* __restrict__ edges, int* __restrict__ cnt){
  int bid = blockIdx.x;                  // 5000
  int g = bid & 7, chunk = bid >> 3;     // chunk 0..624
  int e = chunk*256 + threadIdx.x;
  int d = edges[((size_t)g*NEDGES + e)*2];
  atomicAdd(&cnt[g*NNODES + d], 1);
}

// parallel scan, phase A: per-chunk local exclusive scan + chunk totals
__global__ __launch_bounds__(256) void scanA_kernel(const int* __restrict__ cnt,
                                                    int* __restrict__ off,
                                                    int* __restrict__ tsum){
  __shared__ int sc[256];
  int bid = blockIdx.x;                  // 320
  int g = bid & 7, c = bid >> 3;         // c 0..39
  int t = threadIdx.x;
  int i = c*256 + t;
  int v = (i < NNODES) ? cnt[g*NNODES + i] : 0;
  sc[t] = v;
  __syncthreads();
  for (int o=1;o<256;o<<=1){
    int u = (t>=o) ? sc[t-o] : 0;
    __syncthreads();
    sc[t] += u;
    __syncthreads();
  }
  if (i < NNODES) off[g*(NNODES+1) + i] = sc[t] - v;
  if (t == 255) tsum[g*40 + c] = sc[255];
}
// phase C: add chunk-prefix base; write bucket-count total
__global__ __launch_bounds__(256) void scanC_kernel(const int* __restrict__ tsum,
                                                    int* __restrict__ off){
  __shared__ int ts[40];
  int bid = blockIdx.x;                  // 320
  int g = bid & 7, c = bid >> 3;
  int t = threadIdx.x;
  if (t < 40) ts[t] = tsum[g*40 + t];
  __syncthreads();
  int base = 0;
  for (int k=0;k<40;k++) base += (k < c) ? ts[k] : 0;
  int i = c*256 + t;
  if (i < NNODES) off[g*(NNODES+1) + i] += base;
  if (c == 39 && t == 0){
    int tot = 0;
    for (int k=0;k<40;k++) tot += ts[k];
    off[g*(NNODES+1) + NNODES] = tot;
  }
}

__global__ void scatter_kernel(const int* __restrict__ edges, const int* __restrict__ off,
                               int* __restrict__ cur, int* __restrict__ ssrc){
  int bid = blockIdx.x;                  // 5000
  int g = bid & 7, chunk = bid >> 3;
  int e = chunk*256 + threadIdx.x;
  const int* ep = &edges[((size_t)g*NEDGES + e)*2];
  int d = ep[0], s = ep[1];
  int pos = off[g*(NNODES+1) + d] + atomicAdd(&cur[g*NNODES + d], 1);
  ssrc[g*NEDGES + pos] = s;
}

// ====== 128x128 8-wave counted-vmcnt pipelined MFMA core ======
template<int KP, int RS, int KM>
__device__ __forceinline__ void mm128_core(
    const unsigned short* __restrict__ Ab, const unsigned short* __restrict__ Wb,
    unsigned short* lds, floatx4 (&acc)[4][2])
{
  const int t = threadIdx.x;
  const int w = t >> 6, lane = t & 63;
  const int q = lane >> 4, col = lane & 15;
  const int wr = (w >> 2) * 64;
  const int wc = (w & 3) * 32;
  const int sr = t >> 3;                 // 0..63
  const int sk = ((t & 7) ^ (sr & 7)) * 8;

  auto STAGE = [&](int kb, int buf){
    unsigned short* Al = lds + buf*16384;
    unsigned short* Bl = Al + 8192;
    #pragma unroll
    for (int i=0;i<2;i++){
      int r = i*64 + sr;
      glds16(&Al[i*4096 + w*512], &Ab[(size_t)r*RS + ((kb + sk) & KM)]);
      glds16(&Bl[i*4096 + w*512], &Wb[(size_t)r*KP + kb + sk]);
    }
  };

  STAGE(0, 0);
  int cur = 0;
  #pragma unroll
  for (int kb = 0; kb < KP; kb += 64){
    if (kb + 64 < KP){
      STAGE(kb + 64, cur^1);
      VMCNT4;
    } else {
      VMCNT0;
    }
    SBAR; SCHEDB;
    const unsigned short* Al = lds + cur*16384;
    const unsigned short* Bl = Al + 8192;
    #pragma unroll
    for (int ks2=0; ks2<2; ks2++){
      bf16x8 a[4], bf[2];
      #pragma unroll
      for (int mi=0;mi<4;mi++){
        int r = wr + mi*16 + col;
        int j = (ks2*4 + q) ^ (r & 7);
        a[mi] = *(const bf16x8*)&Al[r*64 + j*8];
      }
      #pragma unroll
      for (int ni=0;ni<2;ni++){
        int r = wc + ni*16 + col;
        int j = (ks2*4 + q) ^ (r & 7);
        bf[ni] = *(const bf16x8*)&Bl[r*64 + j*8];
      }
      PRIO1;
      #pragma unroll
      for (int mi=0;mi<4;mi++)
        #pragma unroll
        for (int ni=0;ni<2;ni++)
          acc[mi][ni] = __builtin_amdgcn_mfma_f32_16x16x32_bf16(a[mi], bf[ni], acc[mi][ni], 0,0,0);
      PRIO0;
    }
    SCHEDB; LGKM0; SBAR;
    cur ^= 1;
  }
}

// ====== fused dual-GEMM 64x128 8-wave pipelined core (gruB) ======
__device__ __forceinline__ void mm64x2_core(
    const unsigned short* __restrict__ A1, const unsigned short* __restrict__ W1,
    const unsigned short* __restrict__ A2, const unsigned short* __restrict__ W2,
    unsigned short* lds, floatx4 (&ai)[4], floatx4 (&ah)[4])
{
  const int t = threadIdx.x;
  const int w = t >> 6, lane = t & 63;
  const int q = lane >> 4, col = lane & 15;
  const int wc = w*16;
  const int sr = t >> 3;                 // 0..63
  const int sk = ((t & 7) ^ (sr & 7)) * 8;

  auto STAGE = [&](int s, int buf){
    const unsigned short* A = (s < 8) ? A1 : A2;
    const unsigned short* W = (s < 8) ? W1 : W2;
    int kb = (s & 7) * 64;
    unsigned short* Al = lds + buf*12288;
    unsigned short* Bl = Al + 4096;
    glds16(&Al[w*512], &A[(size_t)sr*512 + ((kb + sk) & 255)]);
    #pragma unroll
    for (int i=0;i<2;i++){
      int r = i*64 + sr;
      glds16(&Bl[i*4096 + w*512], &W[(size_t)r*512 + kb + sk]);
    }
  };

  STAGE(0, 0);
  int cur = 0;
  #pragma unroll
  for (int s = 0; s < 16; s++){
    if (s < 15){
      STAGE(s + 1, cur^1);
      VMCNT3;
    } else {
      VMCNT0;
    }
    SBAR; SCHEDB;
    const unsigned short* Al = lds + cur*12288;
    const unsigned short* Bl = Al + 4096;
    #pragma unroll
    for (int ks2=0; ks2<2; ks2++){
      bf16x8 a[4], bf;
      #pragma unroll
      for (int mi=0;mi<4;mi++){
        int r = mi*16 + col;
        int j = (ks2*4 + q) ^ (r & 7);
        a[mi] = *(const bf16x8*)&Al[r*64 + j*8];
      }
      {
        int r = wc + col;
        int j = (ks2*4 + q) ^ (r & 7);
        bf = *(const bf16x8*)&Bl[r*64 + j*8];
      }
      PRIO1;
      if (s < 8){
        #pragma unroll
        for (int mi=0;mi<4;mi++)
          ai[mi] = __builtin_amdgcn_mfma_f32_16x16x32_bf16(a[mi], bf, ai[mi], 0,0,0);
      } else {
        #pragma unroll
        for (int mi=0;mi<4;mi++)
          ah[mi] = __builtin_amdgcn_mfma_f32_16x16x32_bf16(a[mi], bf, ah[mi], 0,0,0);
      }
      PRIO0;
    }
    SCHEDB; LGKM0; SBAR;
    cur ^= 1;
  }
}

// XCD-aligned 1-D grid decode: row-block rb lands on XCD rb%8.
#define XDECODE(NCOL) \
  const int bid_ = blockIdx.x; \
  const int rb_ = ((bid_ >> 3) / NCOL) * 8 + (bid_ & 7); \
  const int colb_ = (bid_ >> 3) % NCOL; \
  if (rb_ >= RBLK) return;

#define XDECODE128(NCOL) \
  const int bid_ = blockIdx.x; \
  const int rb_ = ((bid_ >> 3) / NCOL) * 8 + (bid_ & 7); \
  const int colb_ = (bid_ >> 3) % NCOL; \
  if (rb_ >= RBLK128) return;

#define MMPRO128 \
  const int t = threadIdx.x, w = t >> 6, lane = t & 63; \
  const int q = lane >> 4, col = lane & 15; \
  const int wrq = (w >> 2) * 64, wcq = (w & 3) * 32; \
  floatx4 acc[4][2]; \
  _Pragma("unroll") for (int mi=0;mi<4;mi++) _Pragma("unroll") for (int ni=0;ni<2;ni++) \
    acc[mi][ni] = (floatx4){0.f,0.f,0.f,0.f};

// ---- Z = leaky(h @ W1cat^T + b1): NCOL=4; h read from ihcat h-half ----
__global__ __launch_bounds__(512,4) void z64_kernel(
    const unsigned short* __restrict__ ihcat, const unsigned short* __restrict__ w1cat,
    const float* __restrict__ eb1, unsigned short* __restrict__ Z)
{
  __shared__ unsigned short lds[32768];
  XDECODE128(4)
  const int row0 = rb_*128, col0 = colb_*128;
  MMPRO128
  mm128_core<256,512,255>(ihcat + (size_t)row0*512 + 256, w1cat + (size_t)col0*256, lds, acc);

  #pragma unroll
  for (int ni=0;ni<2;ni++){
    int n = col0 + wcq + ni*16 + col;
    int si = n >> 8, cz = n & 255;
    float bb = eb1[si*256 + cz];
    unsigned short* zp = Z + (size_t)si*MROWS*256 + cz;
    #pragma unroll
    for (int mi=0;mi<4;mi++)
      #pragma unroll
      for (int rr=0;rr<4;rr++){
        int row = row0 + wrq + mi*16 + q*4 + rr;
        zp[(size_t)row*256] = f2bf_u(leakyf(acc[mi][ni][rr] + bb));
      }
  }
}

// ---- CSR aggregate, XCD-pinned to stream: g = bid & 7 ----
// Paired-row gather, 16 rows in flight. __launch_bounds__(256,2) raises the
// VGPR cap to 256 so s[16]+u[16] (80 VGPR) actually stay live -> the 16
// gathers issue back-to-back instead of the 2-at-a-time serialization the
// 56-VGPR build produced. FP sum order unchanged (sequential 4-groups).
#define ACC4(B) do { \
  a0 += bfdec(u[B][0])+bfdec(u[B+1][0])+bfdec(u[B+2][0])+bfdec(u[B+3][0]); \
  a1 += bfdec(u[B][1])+bfdec(u[B+1][1])+bfdec(u[B+2][1])+bfdec(u[B+3][1]); \
  a2 += bfdec(u[B][2])+bfdec(u[B+1][2])+bfdec(u[B+2][2])+bfdec(u[B+3][2]); \
  a3 += bfdec(u[B][3])+bfdec(u[B+1][3])+bfdec(u[B+2][3])+bfdec(u[B+3][3]); \
  a4 += bfdec(u[B][4])+bfdec(u[B+1][4])+bfdec(u[B+2][4])+bfdec(u[B+3][4]); \
  a5 += bfdec(u[B][5])+bfdec(u[B+1][5])+bfdec(u[B+2][5])+bfdec(u[B+3][5]); \
  a6 += bfdec(u[B][6])+bfdec(u[B+1][6])+bfdec(u[B+2][6])+bfdec(u[B+3][6]); \
  a7 += bfdec(u[B][7])+bfdec(u[B+1][7])+bfdec(u[B+2][7])+bfdec(u[B+3][7]); \
} while(0)

__global__ __launch_bounds__(256,2) void aggregate_kernel(
    const unsigned short* __restrict__ Z, const int* __restrict__ ssrc,
    const int* __restrict__ off, unsigned short* __restrict__ Sb)
{
  const int bid = blockIdx.x;          // 5000
  const int g = bid & 7;
  const int dgrp = bid >> 3;           // 0..624
  const int b = g >> 1, si = g & 1;
  const int w = threadIdx.x >> 6, lane = threadIdx.x & 63;
  const int half = lane >> 5, c = lane & 31;
  const unsigned short* zb = Z + ((size_t)si*MROWS + b*10000)*256 + c*8;
  const int* sp = ssrc + (size_t)g*NEDGES;
  const int* offg = off + g*(NNODES+1);

  #pragma unroll
  for (int p=0;p<2;p++){
    const int d = dgrp*16 + w*4 + p*2 + half;
    int j = offg[d];
    const int j1 = offg[d+1];
    float a0=0.f,a1=0.f,a2=0.f,a3=0.f,a4=0.f,a5=0.f,a6=0.f,a7=0.f;
    for (; j+16 <= j1; j+=16){
      int s[16];
      #pragma unroll
      for (int e=0;e<16;e++) s[e] = sp[j+e];
      ushort8v u[16];
      #pragma unroll
      for (int e=0;e<16;e++) u[e] = *(const ushort8v*)&zb[(size_t)s[e]*256];
      ACC4(0); ACC4(4); ACC4(8); ACC4(12);
    }
    for (; j+4 <= j1; j+=4){
      int s[4];
      #pragma unroll
      for (int e=0;e<4;e++) s[e] = sp[j+e];
      ushort8v u[4];
      #pragma unroll
      for (int e=0;e<4;e++) u[e] = *(const ushort8v*)&zb[(size_t)s[e]*256];
      ACC4(0);
    }
    for (; j < j1; j++){
      ushort8v uu = *(const ushort8v*)&zb[(size_t)sp[j]*256];
      a0+=bfdec(uu[0]); a1+=bfdec(uu[1]); a2+=bfdec(uu[2]); a3+=bfdec(uu[3]);
      a4+=bfdec(uu[4]); a5+=bfdec(uu[5]); a6+=bfdec(uu[6]); a7+=bfdec(uu[7]);
    }
    size_t so = (size_t)(b*10000 + d)*512 + si*256 + c*8;
    ushort8v hv;
    hv[0]=f2bf_u(a0); hv[1]=f2bf_u(a1); hv[2]=f2bf_u(a2); hv[3]=f2bf_u(a3);
    hv[4]=f2bf_u(a4); hv[5]=f2bf_u(a5); hv[6]=f2bf_u(a6); hv[7]=f2bf_u(a7);
    *(ushort8v*)&Sb[so] = hv;
  }
}

// ---- ihcat.ib = S @ W2k^T (2-term K'=1024) + deg.b2: NCOL=2 ----
__global__ __launch_bounds__(512,4) void w264_kernel(
    const unsigned short* __restrict__ Sb, const unsigned short* __restrict__ w2k,
    const float* __restrict__ eb2, const int* __restrict__ off,
    unsigned short* __restrict__ ihcat)
{
  __shared__ unsigned short lds[32768];
  XDECODE128(2)
  const int row0 = rb_*128, col0 = colb_*128;
  MMPRO128
  mm128_core<1024,512,511>(Sb + (size_t)row0*512, w2k + (size_t)col0*1024, lds, acc);

  float b20[2], b21[2];
  #pragma unroll
  for (int ni=0;ni<2;ni++){
    int n = col0 + wcq + ni*16 + col;
    b20[ni] = eb2[n];
    b21[ni] = eb2[256 + n];
  }
  #pragma unroll
  for (int mi=0;mi<4;mi++)
    #pragma unroll
    for (int rr=0;rr<4;rr++){
      int row = row0 + wrq + mi*16 + q*4 + rr;
      int rw = (row < 40000) ? row : 39999;   // guard padding rows (off lookup only)
      int b = rw / 10000, d = rw - b*10000;
      int o0 = (b*2)*(NNODES+1) + d;
      int o1 = (b*2+1)*(NNODES+1) + d;
      float dg0 = (float)(off[o0+1] - off[o0]);
      float dg1 = (float)(off[o1+1] - off[o1]);
      #pragma unroll
      for (int ni=0;ni<2;ni++){
        int n = col0 + wcq + ni*16 + col;
        ihcat[(size_t)row*512 + n] = f2bf_u(acc[mi][ni][rr] + dg0*b20[ni] + dg1*b21[ni]);
      }
    }
}

// ---- gruA: combined r,z GEMM -> u16 gates. NCOL=4 ----
__global__ __launch_bounds__(512,4) void gruA_kernel(
    const unsigned short* __restrict__ ihcat, const unsigned short* __restrict__ wcomb,
    const float* __restrict__ b_ih, const float* __restrict__ b_hh,
    unsigned short* __restrict__ rz_r, unsigned short* __restrict__ rz_z)
{
  __shared__ unsigned short lds[32768];
  XDECODE128(4)
  const int row0 = rb_*128, col0 = colb_*128;
  MMPRO128
  mm128_core<1024,512,511>(ihcat + (size_t)row0*512, wcomb + (size_t)col0*1024, lds, acc);

  float bb[2];
  #pragma unroll
  for (int ni=0;ni<2;ni++){
    int n = col0 + wcq + ni*16 + col;
    bb[ni] = b_ih[n] + b_hh[n];
  }
  unsigned short* dst = (col0 < 256) ? rz_r : rz_z;
  const int cbase = (col0 & 255) + wcq;
  #pragma unroll
  for (int mi=0;mi<4;mi++)
    #pragma unroll
    for (int rr=0;rr<4;rr++){
      size_t row = (size_t)(row0 + wrq + mi*16 + q*4 + rr);
      #pragma unroll
      for (int ni=0;ni<2;ni++){
        float v = fsig(acc[mi][ni][rr] + bb[ni]);
        dst[row*256 + cbase + ni*16 + col] = (unsigned short)(v*GATE_SCL + 0.5f);
      }
    }
}

// ---- gruB: n gate + GRU update. NCOL=2. Writes ihcat_nxt h-half + h_lo ----
__global__ __launch_bounds__(512,4) void gruB_kernel(
    const unsigned short* __restrict__ ihcat, unsigned short* __restrict__ h_lo,
    const unsigned short* __restrict__ wihk, const unsigned short* __restrict__ whhk,
    const float* __restrict__ b_ih, const float* __restrict__ b_hh,
    const unsigned short* __restrict__ rz_r, const unsigned short* __restrict__ rz_z,
    unsigned short* __restrict__ ihcat_nxt)
{
  __shared__ unsigned short lds[24576];
  XDECODE(2)
  const int row0 = rb_*64, dcol0 = colb_*128;   // n-gate W cols = 512 + dcol0
  const int t = threadIdx.x, w = t >> 6, lane = t & 63;
  const int q = lane >> 4, col = lane & 15;

  floatx4 ai[4], ah[4];
  #pragma unroll
  for (int mi=0;mi<4;mi++){ ai[mi] = (floatx4){0.f,0.f,0.f,0.f}; ah[mi] = (floatx4){0.f,0.f,0.f,0.f}; }

  mm64x2_core(ihcat + (size_t)row0*512,       wihk + (size_t)(512 + dcol0)*512,
              ihcat + (size_t)row0*512 + 256, whhk + (size_t)(512 + dcol0)*512,
              lds, ai, ah);

  const int dn = dcol0 + w*16 + col;
  const float bi = b_ih[512 + dn];
  const float bh = b_hh[512 + dn];
  #pragma unroll
  for (int mi=0;mi<4;mi++)
    #pragma unroll
    for (int rr=0;rr<4;rr++){
      size_t row = (size_t)(row0 + mi*16 + q*4 + rr);
      float rg = (float)rz_r[row*256 + dn] * GATE_INV;
      float zg = (float)rz_z[row*256 + dn] * GATE_INV;
      float ng = ftanh(ai[mi][rr] + bi + rg*(ah[mi][rr] + bh));
      float hv = bfdec(ihcat[row*512 + 256 + dn]) + bfdec(h_lo[row*256 + dn]);
      float hnew = (1.f - zg)*ng + zg*hv;
      unsigned short hh = f2bf_u(hnew);
      ihcat_nxt[row*512 + 256 + dn] = hh;
      h_lo[row*256 + dn] = f2bf_u(hnew - bfdec(hh));
    }
}

__global__ void reduce_kernel(const unsigned short* __restrict__ ihcat,
                              const unsigned short* __restrict__ h_lo,
                              float* __restrict__ sbuf){
  int b  = blockIdx.x / 50;
  int s0 = (blockIdx.x % 50) * 200;
  int d  = threadIdx.x;
  size_t row = (size_t)b*NNODES + s0;
  float acc = 0.f;
  for (int i=0;i<200;i++){
    acc += bfdec(ihcat[(row+i)*512 + 256 + d]) + bfdec(h_lo[(row+i)*256 + d]);
  }
  atomicAdd(&sbuf[b*DIM + d], acc);
}

__global__ __launch_bounds__(320) void head_kernel(
    const float* __restrict__ sbuf, const float* __restrict__ pt,
    const float* __restrict__ fc1w, const float* __restrict__ fc1b,
    const float* __restrict__ fc2w, const float* __restrict__ fc2b,
    const float* __restrict__ fc3w, const float* __restrict__ fc3b,
    float* __restrict__ out)
{
  __shared__ float L[4][257];
  __shared__ float T1[4][80];
  __shared__ float T2[4][80];
  __shared__ float fmx[4];
  int t = threadIdx.x;
  if (t < 256){
    for (int b=0;b<4;b++){
      float v = sbuf[b*DIM + t];
      float ll = logf(v);
      if (ll != ll) ll = 0.f;
      ll = fmaxf(ll, 0.f);
      L[b][t] = ll;
    }
  }
  __syncthreads();
  int w = t >> 6, lane = t & 63;
  if (w < 4){
    float m = -INFINITY;
    for (int i=lane;i<256;i+=64){ float v = L[w][i]; if (v != INFINITY) m = fmaxf(m, v); }
    #pragma unroll
    for (int o=32;o>=1;o>>=1) m = fmaxf(m, __shfl_xor(m, o, 64));
    if (lane==0) fmx[w] = m;
  }
  __syncthreads();
  if (t < 256){
    for (int b=0;b<4;b++) if (L[b][t] == INFINITY) L[b][t] = fmx[b];
  }
  if (t < 4) L[t][256] = pt[t];
  __syncthreads();
  if (t < 320){
    int b = t/80, i = t%80;
    float a = fc1b[i];
    for (int k=0;k<257;k++) a += L[b][k]*fc1w[i*257+k];
    T1[b][i] = leakyf(a);
  }
  __syncthreads();
  if (t < 320){
    int b = t/80, i = t%80;
    float a = fc2b[i];
    for (int k=0;k<80;k++) a += T1[b][k]*fc2w[i*80+k];
    T2[b][i] = leakyf(a);
  }
  __syncthreads();
  if (t < 40){
    int b = t/10, i = t%10;
    float a = fc3b[i];
    for (int k=0;k<80;k++) a += T2[b][k]*fc3w[i*80+k];
    out[b*10+i] = a;
  }
}

extern "C" void kernel_launch(void* const* d_in, const int* in_sizes, int n_in,
                              void* d_out, int out_size, void* d_ws, size_t ws_size,
                              hipStream_t stream) {
  const float* nodes = (const float*)d_in[0];
  const int*   edges = (const int*)d_in[1];
  const float* pt    = (const float*)d_in[2];
  const float* w_ih  = (const float*)d_in[3];
  const float* w_hh  = (const float*)d_in[4];
  const float* b_ih  = (const float*)d_in[5];
  const float* b_hh  = (const float*)d_in[6];
  const float* ew1   = (const float*)d_in[7];
  const float* eb1   = (const float*)d_in[8];
  const float* ew2   = (const float*)d_in[9];
  const float* eb2   = (const float*)d_in[10];
  const float* fc1w  = (const float*)d_in[11];
  const float* fc1b  = (const float*)d_in[12];
  const float* fc2w  = (const float*)d_in[13];
  const float* fc2b  = (const float*)d_in[14];
  const float* fc3w  = (const float*)d_in[15];
  const float* fc3b  = (const float*)d_in[16];

  const size_t HN  = (size_t)BATCH*NNODES*DIM;    // 10,240,000 (real rows)
  const size_t HNP = (size_t)MROWS*DIM;
  char* p = (char*)d_ws;
  float* sbuf = (float*)p;                        p += BATCH*DIM*4;
  unsigned short* ihcat0 = (unsigned short*)p;    p += (size_t)MROWS*512*2;  // [ib | h]
  unsigned short* ihcat1 = (unsigned short*)p;    p += (size_t)MROWS*512*2;
  unsigned short* h_lo   = (unsigned short*)p;    p += HNP*2;
  unsigned short* Zb   = (unsigned short*)p;      p += 2*HNP*2;              // z/agg scratch
  unsigned short* Sb   = (unsigned short*)p;      p += (size_t)MROWS*512*2;  // dead after w2 -> rz
  unsigned short* w1cat= (unsigned short*)p;      p += 512*256*2;
  unsigned short* w2k  = (unsigned short*)p;      p += 256*1024*2;
  unsigned short* wihk = (unsigned short*)p;      p += 768*512*2;
  unsigned short* whhk = (unsigned short*)p;      p += 768*512*2;
  unsigned short* wcomb= (unsigned short*)p;      p += 512*1024*2;
  int* off  = (int*)p;                            p += NG*(NNODES+1)*4;
  int* cur  = (int*)p;                            p += NG*NNODES*4;
  int* ssrc = (int*)p;                            p += (size_t)NG*NEDGES*4;

  unsigned short* rz_r = (unsigned short*)Sb;              // MROWS*256 u16
  unsigned short* rz_z = rz_r + (size_t)MROWS*256;         // MROWS*256 u16
  int* tsum = (int*)sbuf;   // 8*40 ints; sbuf is memset AFTER scan/scatter

  // weights
  w1cat_kernel<<<512,256,0,stream>>>(ew1, w1cat);
  w2k_kernel<<<1024,256,0,stream>>>(ew2, w2k);
  wk2_kernel<<<1536,256,0,stream>>>(w_ih, wihk);
  wk2_kernel<<<1536,256,0,stream>>>(w_hh, whhk);
  wcomb_kernel<<<2048,256,0,stream>>>(w_ih, w_hh, wcomb);

  // h0
  ihinit_kernel<<<(int)(HN/1024),256,0,stream>>>(nodes, ihcat0, h_lo);

  // counting sort (CSR) of edges by dst, per stream g (stream pinned to XCD)
  hipMemsetAsync(cur, 0, NG*NNODES*sizeof(int), stream);
  hist_kernel<<<(NG*NEDGES)/256,256,0,stream>>>(edges, cur);
  scanA_kernel<<<NG*40,256,0,stream>>>(cur, off, tsum);
  scanC_kernel<<<NG*40,256,0,stream>>>(tsum, off);
  hipMemsetAsync(cur, 0, NG*NNODES*sizeof(int), stream);
  scatter_kernel<<<(NG*NEDGES)/256,256,0,stream>>>(edges, off, cur, ssrc);

  hipMemsetAsync(sbuf, 0, BATCH*DIM*sizeof(float), stream);

  unsigned short* ih[2] = {ihcat0, ihcat1};

  for (int pass=0; pass<6; pass++){
    unsigned short* curb = ih[pass & 1];
    unsigned short* nxtb = ih[(pass+1) & 1];
    z64_kernel<<<RGRP128*8*4,512,0,stream>>>(curb, w1cat, eb1, Zb);
    aggregate_kernel<<<5000,256,0,stream>>>(Zb, ssrc, off, Sb);
    w264_kernel<<<RGRP128*8*2,512,0,stream>>>(Sb, w2k, eb2, off, curb);
    gruA_kernel<<<RGRP128*8*4,512,0,stream>>>(curb, wcomb, b_ih, b_hh, rz_r, rz_z);
    gruB_kernel<<<RGRP*8*2,512,0,stream>>>(curb, h_lo, wihk, whhk, b_ih, b_hh,
                                           rz_r, rz_z, nxtb);
  }
  reduce_kernel<<<200,256,0,stream>>>(ih[0], h_lo, sbuf);
  head_kernel<<<1,320,0,stream>>>(sbuf, pt, fc1w,fc1b,fc2w,fc2b,fc3w,fc3b,(float*)d_out);
}